// Round 1
// baseline (39288.577 us; speedup 1.0000x reference)
//
#include <hip/hip_runtime.h>
#include <cmath>

// ---------------------------------------------------------------------------
// MutualTimeSformer — fp32 baseline (round 0: correctness + structure)
// Dims: B=1, F=4, n=1200/frame, N=4801 tokens, D=512, HEADS=8, DH=64, DEPTH=12
// ws layout (floats): X[N,512] | XN[N,512] | BIG[N,4096] | MID[N,2048] ~137.7MB
// ---------------------------------------------------------------------------

#define NT      4801
#define NP      4800          // patch tokens
#define DM      512
#define NHEADS  8
#define DH      64
#define QKV_ST  1536
#define ATT_SCALE 0.125f      // 64^-0.5
#define LN_EPS  1e-5f

// ------------------------------ patchify -----------------------------------
__global__ void patchify_kernel(const float* __restrict__ video, float* __restrict__ out)
{
    int idx = blockIdx.x * 256 + threadIdx.x;
    if (idx >= NP * 768) return;
    int tok = idx / 768, e = idx % 768;
    int c  = e % 3;
    int pe = e / 3;            // p1*16 + p2
    int p2 = pe % 16, p1 = pe / 16;
    int half = tok / 2400, r = tok % 2400;
    int f = r / 600, rr = r % 600;
    int hi = rr / 20, wi = rr % 20;
    int row = hi * 16 + p1;
    int col = half * 320 + wi * 16 + p2;
    out[idx] = video[(((size_t)f * 3 + c) * 480 + row) * 640 + col];
}

__global__ void cls_init_kernel(const float* __restrict__ cls_token,
                                const float* __restrict__ pos, float* __restrict__ X)
{
    int d = blockIdx.x * 256 + threadIdx.x;
    if (d < DM) X[d] = cls_token[d] + pos[d];
}

// ------------------------------ GEMM ---------------------------------------
// C[M,N] = A[M,K] @ B[K,N] (+bias[N]) (+add[M,N]) ; 128x128 tile, BK=16, 8x8/thread
__global__ __launch_bounds__(256) void gemm_kernel(
    const float* __restrict__ A, const float* __restrict__ B,
    const float* __restrict__ bias, const float* __restrict__ add,
    float* __restrict__ C, int M, int N, int K)
{
    __shared__ float As[16][128];   // [k][m]
    __shared__ float Bs[16][128];   // [k][n]
    int tid = threadIdx.x;
    int row0 = blockIdx.y * 128, col0 = blockIdx.x * 128;
    int tx = tid % 16, ty = tid / 16;

    float acc[8][8];
    #pragma unroll
    for (int i = 0; i < 8; i++)
        #pragma unroll
        for (int j = 0; j < 8; j++) acc[i][j] = 0.f;

    for (int k0 = 0; k0 < K; k0 += 16) {
        #pragma unroll
        for (int i = 0; i < 2; i++) {                 // A tile: 128x16
            int p = tid + i * 256;
            int arow = p >> 2, kq = (p & 3) * 4;
            int gr = row0 + arow;
            float4 av = make_float4(0.f, 0.f, 0.f, 0.f);
            if (gr < M) av = *(const float4*)&A[(size_t)gr * K + k0 + kq];
            As[kq + 0][arow] = av.x; As[kq + 1][arow] = av.y;
            As[kq + 2][arow] = av.z; As[kq + 3][arow] = av.w;
        }
        #pragma unroll
        for (int i = 0; i < 2; i++) {                 // B tile: 16x128
            int p = tid + i * 256;
            int brow = p >> 5, bq = (p & 31) * 4;
            *(float4*)&Bs[brow][bq] = *(const float4*)&B[(size_t)(k0 + brow) * N + col0 + bq];
        }
        __syncthreads();
        #pragma unroll
        for (int kk = 0; kk < 16; kk++) {
            float4 a0 = *(float4*)&As[kk][ty * 8];
            float4 a1 = *(float4*)&As[kk][ty * 8 + 4];
            float4 b0 = *(float4*)&Bs[kk][tx * 8];
            float4 b1 = *(float4*)&Bs[kk][tx * 8 + 4];
            float a[8] = {a0.x, a0.y, a0.z, a0.w, a1.x, a1.y, a1.z, a1.w};
            float b[8] = {b0.x, b0.y, b0.z, b0.w, b1.x, b1.y, b1.z, b1.w};
            #pragma unroll
            for (int i = 0; i < 8; i++)
                #pragma unroll
                for (int j = 0; j < 8; j++) acc[i][j] += a[i] * b[j];
        }
        __syncthreads();
    }

    #pragma unroll
    for (int i = 0; i < 8; i++) {
        int gr = row0 + ty * 8 + i;
        if (gr < M) {
            #pragma unroll
            for (int j = 0; j < 8; j++) {
                int gc = col0 + tx * 8 + j;
                float v = acc[i][j];
                if (bias) v += bias[gc];
                if (add)  v += add[(size_t)gr * N + gc];
                C[(size_t)gr * N + gc] = v;
            }
        }
    }
}

// ------------------------------ LayerNorm ----------------------------------
// one wave per row (512 elems, 8/lane)
__global__ __launch_bounds__(256) void ln_kernel(
    const float* __restrict__ x, const float* __restrict__ g,
    const float* __restrict__ b, float* __restrict__ y, int M)
{
    int wid = threadIdx.x >> 6, lane = threadIdx.x & 63;
    int row = blockIdx.x * 4 + wid;
    if (row >= M) return;
    const float4* xr = (const float4*)(x + (size_t)row * DM);
    float4 v0 = xr[lane * 2], v1 = xr[lane * 2 + 1];
    float s  = v0.x + v0.y + v0.z + v0.w + v1.x + v1.y + v1.z + v1.w;
    float s2 = v0.x*v0.x + v0.y*v0.y + v0.z*v0.z + v0.w*v0.w
             + v1.x*v1.x + v1.y*v1.y + v1.z*v1.z + v1.w*v1.w;
    #pragma unroll
    for (int off = 32; off >= 1; off >>= 1) {
        s  += __shfl_xor(s, off);
        s2 += __shfl_xor(s2, off);
    }
    float mu = s * (1.f / DM);
    float var = s2 * (1.f / DM) - mu * mu;
    float r = rsqrtf(var + LN_EPS);
    const float4* gv = (const float4*)g;
    const float4* bv = (const float4*)b;
    float4* yr = (float4*)(y + (size_t)row * DM);
    #pragma unroll
    for (int i = 0; i < 2; i++) {
        float4 v = (i == 0) ? v0 : v1;
        float4 gg = gv[lane * 2 + i], bb = bv[lane * 2 + i];
        float4 o;
        o.x = (v.x - mu) * r * gg.x + bb.x;
        o.y = (v.y - mu) * r * gg.y + bb.y;
        o.z = (v.z - mu) * r * gg.z + bb.z;
        o.w = (v.w - mu) * r * gg.w + bb.w;
        yr[lane * 2 + i] = o;
    }
}

// ------------------------------ attention ----------------------------------
__device__ __forceinline__ float dot64(const float4* q, const float* row)
{
    const float4* r4 = (const float4*)row;
    float s = 0.f;
    #pragma unroll
    for (int i = 0; i < 16; i++) {
        float4 k = r4[i];
        s += q[i].x * k.x + q[i].y * k.y + q[i].z * k.z + q[i].w * k.w;
    }
    return s;
}

// time attention: query (h, patch j) attends {cls} U {same pos across 4 frames}
__global__ __launch_bounds__(256) void time_attn_kernel(
    const float* __restrict__ qkv, float* __restrict__ out)
{
    int t = blockIdx.x * 256 + threadIdx.x;
    if (t >= NHEADS * NP) return;
    int h = t / NP, j = t % NP;
    int pos = j % 1200;
    const float4* qr = (const float4*)(qkv + (size_t)(j + 1) * QKV_ST + h * DH);
    float4 q[16];
    #pragma unroll
    for (int i = 0; i < 16; i++) {
        q[i] = qr[i];
        q[i].x *= ATT_SCALE; q[i].y *= ATT_SCALE; q[i].z *= ATT_SCALE; q[i].w *= ATT_SCALE;
    }
    int rows[5] = {0, pos + 1, pos + 1201, pos + 2401, pos + 3601};
    float s[5];
    #pragma unroll
    for (int kk = 0; kk < 5; kk++)
        s[kk] = dot64(q, qkv + (size_t)rows[kk] * QKV_ST + DM + h * DH);
    float mx = s[0];
    #pragma unroll
    for (int kk = 1; kk < 5; kk++) mx = fmaxf(mx, s[kk]);
    float e[5], l = 0.f;
    #pragma unroll
    for (int kk = 0; kk < 5; kk++) { e[kk] = __expf(s[kk] - mx); l += e[kk]; }
    float rl = 1.f / l;
    float4 acc[16];
    #pragma unroll
    for (int i = 0; i < 16; i++) acc[i] = make_float4(0.f, 0.f, 0.f, 0.f);
    #pragma unroll
    for (int kk = 0; kk < 5; kk++) {
        float p = e[kk] * rl;
        const float4* v4 = (const float4*)(qkv + (size_t)rows[kk] * QKV_ST + 2 * DM + h * DH);
        #pragma unroll
        for (int i = 0; i < 16; i++) {
            float4 v = v4[i];
            acc[i].x += p * v.x; acc[i].y += p * v.y;
            acc[i].z += p * v.z; acc[i].w += p * v.w;
        }
    }
    float4* op = (float4*)(out + (size_t)(j + 1) * DM + h * DH);
    #pragma unroll
    for (int i = 0; i < 16; i++) op[i] = acc[i];
}

// space attention: query (h, f, pos) attends {cls} U {other half of same frame}
__global__ __launch_bounds__(256) void space_attn_kernel(
    const float* __restrict__ qkv, float* __restrict__ out)
{
    int t = blockIdx.x * 256 + threadIdx.x;
    if (t >= NHEADS * NP) return;
    int h = t / NP, j = t % NP;
    int f = j / 1200, pos = j % 1200;
    const float4* qr = (const float4*)(qkv + (size_t)(j + 1) * QKV_ST + h * DH);
    float4 q[16];
    #pragma unroll
    for (int i = 0; i < 16; i++) {
        q[i] = qr[i];
        q[i].x *= ATT_SCALE; q[i].y *= ATT_SCALE; q[i].z *= ATT_SCALE; q[i].w *= ATT_SCALE;
    }
    float4 acc[16];
    #pragma unroll
    for (int i = 0; i < 16; i++) acc[i] = make_float4(0.f, 0.f, 0.f, 0.f);
    float m = -INFINITY, l = 0.f;
    int base = f * 1200 + ((pos < 600) ? 600 : 0) + 1;  // first non-cls key row
    #pragma unroll 1
    for (int kk = 0; kk <= 600; kk++) {
        size_t krow = (kk == 0) ? 0 : (size_t)(base + kk - 1);
        const float* kp = qkv + krow * QKV_ST + DM + h * DH;
        float s = dot64(q, kp);
        if (s > m) {
            float c = __expf(m - s);
            l *= c;
            #pragma unroll
            for (int i = 0; i < 16; i++) {
                acc[i].x *= c; acc[i].y *= c; acc[i].z *= c; acc[i].w *= c;
            }
            m = s;
        }
        float p = __expf(s - m);
        l += p;
        const float4* v4 = (const float4*)(kp + DM);
        #pragma unroll
        for (int i = 0; i < 16; i++) {
            float4 v = v4[i];
            acc[i].x += p * v.x; acc[i].y += p * v.y;
            acc[i].z += p * v.z; acc[i].w += p * v.w;
        }
    }
    float rl = 1.f / l;
    float4* op = (float4*)(out + (size_t)(j + 1) * DM + h * DH);
    #pragma unroll
    for (int i = 0; i < 16; i++) {
        float4 o;
        o.x = acc[i].x * rl; o.y = acc[i].y * rl;
        o.z = acc[i].z * rl; o.w = acc[i].w * rl;
        op[i] = o;
    }
}

// cls attends to all 4801 tokens. 1 block (4 waves) per head; lane = dim.
__global__ __launch_bounds__(256) void cls_attn_kernel(
    const float* __restrict__ qkv, float* __restrict__ out)
{
    int h = blockIdx.x;
    int wid = threadIdx.x >> 6, lane = threadIdx.x & 63;
    __shared__ float sm[4], sl[4], sacc[4][64];
    float qv = qkv[h * DH + lane] * ATT_SCALE;   // token 0 q
    float m = -INFINITY, l = 0.f, acc = 0.f;
    for (int key = wid; key < NT; key += 4) {
        const float* kr = qkv + (size_t)key * QKV_ST + DM + h * DH;
        float s = qv * kr[lane];
        #pragma unroll
        for (int off = 32; off >= 1; off >>= 1) s += __shfl_xor(s, off);
        float vv = kr[DM + lane];                // v row
        if (s > m) {
            float c = __expf(m - s);
            l *= c; acc *= c; m = s;
        }
        float p = __expf(s - m);
        l += p; acc += p * vv;
    }
    if (lane == 0) { sm[wid] = m; sl[wid] = l; }
    sacc[wid][lane] = acc;
    __syncthreads();
    if (wid == 0) {
        float M2 = fmaxf(fmaxf(sm[0], sm[1]), fmaxf(sm[2], sm[3]));
        float L = 0.f, o = 0.f;
        #pragma unroll
        for (int w = 0; w < 4; w++) {
            float c = __expf(sm[w] - M2);
            L += sl[w] * c;
            o += sacc[w][lane] * c;
        }
        out[h * DH + lane] = o / L;   // token 0 row of attn_out
    }
}

// ------------------------------ GeGLU --------------------------------------
__global__ __launch_bounds__(256) void geglu_kernel(
    const float* __restrict__ h, float* __restrict__ out, int M)
{
    int idx = blockIdx.x * 256 + threadIdx.x;     // float4 index over [M,2048]
    if (idx >= M * 512) return;
    int t = idx / 512, jq = idx % 512;
    float4 u = *(const float4*)&h[(size_t)t * 4096 + jq * 4];
    float4 g = *(const float4*)&h[(size_t)t * 4096 + 2048 + jq * 4];
    float4 o;
    o.x = u.x * 0.5f * g.x * (1.f + erff(g.x * 0.70710678f));
    o.y = u.y * 0.5f * g.y * (1.f + erff(g.y * 0.70710678f));
    o.z = u.z * 0.5f * g.z * (1.f + erff(g.z * 0.70710678f));
    o.w = u.w * 0.5f * g.w * (1.f + erff(g.w * 0.70710678f));
    *(float4*)&out[(size_t)t * 2048 + jq * 4] = o;
}

// ------------------------------ head ---------------------------------------
__global__ __launch_bounds__(64) void head_kernel(
    const float* __restrict__ x, const float* __restrict__ g,
    const float* __restrict__ b, const float* __restrict__ w,
    const float* __restrict__ ob, float* __restrict__ out)
{
    __shared__ float xn[DM];
    int lane = threadIdx.x;
    const float4* xr = (const float4*)x;          // row 0
    float4 v0 = xr[lane * 2], v1 = xr[lane * 2 + 1];
    float s  = v0.x + v0.y + v0.z + v0.w + v1.x + v1.y + v1.z + v1.w;
    float s2 = v0.x*v0.x + v0.y*v0.y + v0.z*v0.z + v0.w*v0.w
             + v1.x*v1.x + v1.y*v1.y + v1.z*v1.z + v1.w*v1.w;
    #pragma unroll
    for (int off = 32; off >= 1; off >>= 1) {
        s  += __shfl_xor(s, off);
        s2 += __shfl_xor(s2, off);
    }
    float mu = s * (1.f / DM);
    float var = s2 * (1.f / DM) - mu * mu;
    float r = rsqrtf(var + LN_EPS);
    #pragma unroll
    for (int i = 0; i < 8; i++) {
        int d = lane * 8 + i;
        xn[d] = (x[d] - mu) * r * g[d] + b[d];
    }
    __syncthreads();
    if (lane < 60) {
        float a = ob[lane];
        for (int d = 0; d < DM; d++) a += xn[d] * w[d * 60 + lane];
        out[lane] = a;
    }
}

// ------------------------------ driver -------------------------------------
extern "C" void kernel_launch(void* const* d_in, const int* in_sizes, int n_in,
                              void* d_out, int out_size, void* d_ws, size_t ws_size,
                              hipStream_t stream)
{
    const float* video     = (const float*)d_in[0];
    const float* patch_w   = (const float*)d_in[1];
    const float* patch_b   = (const float*)d_in[2];
    const float* pos_emb   = (const float*)d_in[3];
    const float* cls_token = (const float*)d_in[4];
    const float* t_ln_g    = (const float*)d_in[5];
    const float* t_ln_b    = (const float*)d_in[6];
    const float* t_qkv_w   = (const float*)d_in[7];
    const float* t_out_w   = (const float*)d_in[8];
    const float* t_out_b   = (const float*)d_in[9];
    const float* s_ln_g    = (const float*)d_in[10];
    const float* s_ln_b    = (const float*)d_in[11];
    const float* s_qkv_w   = (const float*)d_in[12];
    const float* s_out_w   = (const float*)d_in[13];
    const float* s_out_b   = (const float*)d_in[14];
    const float* f_ln_g    = (const float*)d_in[15];
    const float* f_ln_b    = (const float*)d_in[16];
    const float* f_w1      = (const float*)d_in[17];
    const float* f_b1      = (const float*)d_in[18];
    const float* f_w2      = (const float*)d_in[19];
    const float* f_b2      = (const float*)d_in[20];
    const float* o_ln_g    = (const float*)d_in[21];
    const float* o_ln_b    = (const float*)d_in[22];
    const float* o_w       = (const float*)d_in[23];
    const float* o_b       = (const float*)d_in[24];

    float* ws  = (float*)d_ws;
    float* X   = ws;                       // [NT,512]
    float* XN  = X  + (size_t)NT * 512;    // [NT,512]
    float* BIG = XN + (size_t)NT * 512;    // [NT,4096] (also patches [4800,768])
    float* MID = BIG + (size_t)NT * 4096;  // [NT,2048]

    // ---- patch embed + cls + pos ----
    patchify_kernel<<<(NP * 768 + 255) / 256, 256, 0, stream>>>(video, BIG);
    cls_init_kernel<<<2, 256, 0, stream>>>(cls_token, pos_emb, X);
    gemm_kernel<<<dim3(4, 38), 256, 0, stream>>>(BIG, patch_w, patch_b, pos_emb + DM,
                                                 X + DM, NP, DM, 768);

    dim3 g_qkv(12, 38), g_out(4, 38), g_ff1(32, 38), g_ff2(4, 38);
    for (int i = 0; i < 12; i++) {
        // ---- time attention block ----
        ln_kernel<<<1201, 256, 0, stream>>>(X, t_ln_g + i * DM, t_ln_b + i * DM, XN, NT);
        gemm_kernel<<<g_qkv, 256, 0, stream>>>(XN, t_qkv_w + (size_t)i * DM * QKV_ST,
                                               nullptr, nullptr, BIG, NT, QKV_ST, DM);
        time_attn_kernel<<<150, 256, 0, stream>>>(BIG, MID);
        cls_attn_kernel<<<8, 256, 0, stream>>>(BIG, MID);
        gemm_kernel<<<g_out, 256, 0, stream>>>(MID, t_out_w + (size_t)i * DM * DM,
                                               t_out_b + i * DM, X, X, NT, DM, DM);
        // ---- space attention block ----
        ln_kernel<<<1201, 256, 0, stream>>>(X, s_ln_g + i * DM, s_ln_b + i * DM, XN, NT);
        gemm_kernel<<<g_qkv, 256, 0, stream>>>(XN, s_qkv_w + (size_t)i * DM * QKV_ST,
                                               nullptr, nullptr, BIG, NT, QKV_ST, DM);
        space_attn_kernel<<<150, 256, 0, stream>>>(BIG, MID);
        cls_attn_kernel<<<8, 256, 0, stream>>>(BIG, MID);
        gemm_kernel<<<g_out, 256, 0, stream>>>(MID, s_out_w + (size_t)i * DM * DM,
                                               s_out_b + i * DM, X, X, NT, DM, DM);
        // ---- GeGLU FF block ----
        ln_kernel<<<1201, 256, 0, stream>>>(X, f_ln_g + i * DM, f_ln_b + i * DM, XN, NT);
        gemm_kernel<<<g_ff1, 256, 0, stream>>>(XN, f_w1 + (size_t)i * DM * 4096,
                                               f_b1 + i * 4096, nullptr, BIG, NT, 4096, DM);
        geglu_kernel<<<(NT * 512 + 255) / 256, 256, 0, stream>>>(BIG, MID, NT);
        gemm_kernel<<<g_ff2, 256, 0, stream>>>(MID, f_w2 + (size_t)i * 2048 * DM,
                                               f_b2 + i * DM, X, X, NT, DM, 2048);
    }

    head_kernel<<<1, 64, 0, stream>>>(X, o_ln_g, o_ln_b, o_w, o_b, (float*)d_out);
}

// Round 2
// 14166.299 us; speedup vs baseline: 2.7734x; 2.7734x over previous
//
#include <hip/hip_runtime.h>
#include <cmath>

// ---------------------------------------------------------------------------
// MutualTimeSformer — round 1: bf16 MFMA GEMMs + LDS-staged attention
// Dims: B=1, F=4, n=1200/frame, N=4801 tokens (pad 4864), D=512, H=8, DH=64
// ---------------------------------------------------------------------------

#define NT      4801
#define NP      4800
#define MP      4864          // padded row count (38 * 128)
#define DM      512
#define QKV_ST  1536
#define LN_EPS  1e-5f

typedef __attribute__((ext_vector_type(8))) short bf16x8;
typedef __attribute__((ext_vector_type(4))) float f32x4;

__device__ __forceinline__ unsigned short f2b(float f) {
    union { float f; unsigned int u; } x; x.f = f;
    unsigned int r = (x.u + 0x7FFFu + ((x.u >> 16) & 1u)) >> 16;
    return (unsigned short)r;
}
__device__ __forceinline__ float b2f(unsigned short b) {
    union { unsigned int u; float f; } x; x.u = ((unsigned int)b) << 16;
    return x.f;
}
__device__ __forceinline__ unsigned int pack2(float a, float b) {
    return (unsigned int)f2b(a) | ((unsigned int)f2b(b) << 16);
}

__device__ __forceinline__ void gl_lds16(const void* g, void* l) {
    __builtin_amdgcn_global_load_lds(
        (__attribute__((address_space(1))) unsigned int*)(unsigned long long)(uintptr_t)g,
        (__attribute__((address_space(3))) unsigned int*)l, 16, 0, 0);
}

// ------------------------------ patchify (fp32 -> bf16) --------------------
__global__ void patchify_kernel(const float* __restrict__ video, unsigned short* __restrict__ out)
{
    int idx = blockIdx.x * 256 + threadIdx.x;
    if (idx >= NP * 768) return;
    int tok = idx / 768, e = idx % 768;
    int c  = e % 3;
    int pe = e / 3;
    int p2 = pe % 16, p1 = pe / 16;
    int half = tok / 2400, r = tok % 2400;
    int f = r / 600, rr = r % 600;
    int hi = rr / 20, wi = rr % 20;
    int row = hi * 16 + p1;
    int col = half * 320 + wi * 16 + p2;
    out[idx] = f2b(video[(((size_t)f * 3 + c) * 480 + row) * 640 + col]);
}

__global__ void cls_init_kernel(const float* __restrict__ cls_token,
                                const float* __restrict__ pos, float* __restrict__ X)
{
    int d = blockIdx.x * 256 + threadIdx.x;
    if (d < DM) X[d] = cls_token[d] + pos[d];
}

// ------------------------------ weight transpose-convert -------------------
// in [K,N] fp32 -> out [N,K] bf16 (B^T layout for the MFMA GEMM)
__device__ __forceinline__ void transpose_tile(const float* __restrict__ in,
                                               unsigned short* __restrict__ out,
                                               int K, int N, int tile)
{
    __shared__ float T[32][33];
    int ntk = K / 32;
    int kt = tile % ntk, nt = tile / ntk;
    int k0 = kt * 32, n0 = nt * 32;
    int tx = threadIdx.x & 31, ty = threadIdx.x >> 5;
    #pragma unroll
    for (int i = 0; i < 4; i++)
        T[ty + 8 * i][tx] = in[(size_t)(k0 + ty + 8 * i) * N + n0 + tx];
    __syncthreads();
    #pragma unroll
    for (int i = 0; i < 4; i++)
        out[(size_t)(n0 + ty + 8 * i) * K + k0 + tx] = f2b(T[tx][ty + 8 * i]);
}

__global__ __launch_bounds__(256) void convertT_layer(
    const float* __restrict__ w0, const float* __restrict__ w1,
    const float* __restrict__ w2, const float* __restrict__ w3,
    const float* __restrict__ w4, const float* __restrict__ w5,
    unsigned short* __restrict__ out)
{
    int t = blockIdx.x;
    if      (t <  768) transpose_tile(w0, out + 0,       512, 1536, t);
    else if (t < 1024) transpose_tile(w1, out + 786432,  512,  512, t - 768);
    else if (t < 1792) transpose_tile(w2, out + 1048576, 512, 1536, t - 1024);
    else if (t < 2048) transpose_tile(w3, out + 1835008, 512,  512, t - 1792);
    else if (t < 4096) transpose_tile(w4, out + 2097152, 512, 4096, t - 2048);
    else               transpose_tile(w5, out + 4194304, 2048, 512, t - 4096);
}

__global__ __launch_bounds__(256) void convertT_one(
    const float* __restrict__ in, unsigned short* __restrict__ out, int K, int N)
{
    transpose_tile(in, out, K, N, blockIdx.x);
}

// ------------------------------ MFMA GEMM ----------------------------------
// C[M,N] = A[M,K]bf16 @ B[K,N] (BT=[N,K]bf16) (+bias) (+add fp32); out fp32 or bf16
// 128x128 tile, BK=64, 4 waves (2x2), each wave 4x4 frags of 16x16x32.
template<bool OB16>
__global__ __launch_bounds__(256, 2) void mfma_gemm(
    const unsigned short* __restrict__ A, const unsigned short* __restrict__ BT,
    const float* __restrict__ bias, const float* __restrict__ add,
    void* __restrict__ C, int Mv, int N, int K)
{
    __shared__ short Asm[128 * 64];
    __shared__ short Bsm[128 * 64];
    const int tid = threadIdx.x, w = tid >> 6, lane = tid & 63;
    const int row0 = blockIdx.y * 128, col0 = blockIdx.x * 128;
    const int wm = w >> 1, wn = w & 1;
    const int l15 = lane & 15, quad = lane >> 4;

    f32x4 acc[4][4] = {};

    int arows[4], aqs[4];
    #pragma unroll
    for (int i = 0; i < 4; i++) {
        int s = (w * 4 + i) * 64 + lane;      // 16B-slot index 0..1023
        arows[i] = s >> 3;                    // tile row 0..127
        aqs[i]   = (s & 7) ^ ((s >> 3) & 7);  // swizzled source chunk
    }

    for (int k0 = 0; k0 < K; k0 += 64) {
        __syncthreads();
        #pragma unroll
        for (int i = 0; i < 4; i++) {
            gl_lds16(A  + (size_t)(row0 + arows[i]) * K + k0 + aqs[i] * 8,
                     &Asm[(w * 4 + i) * 512]);
            gl_lds16(BT + (size_t)(col0 + arows[i]) * K + k0 + aqs[i] * 8,
                     &Bsm[(w * 4 + i) * 512]);
        }
        __syncthreads();
        #pragma unroll
        for (int ks = 0; ks < 2; ks++) {
            bf16x8 af[4], bfr[4];
            #pragma unroll
            for (int i = 0; i < 4; i++) {
                int m  = wm * 64 + i * 16 + l15;
                int pa = (ks * 4 + quad) ^ (m & 7);
                af[i]  = *(const bf16x8*)&Asm[m * 64 + pa * 8];
                int n  = wn * 64 + i * 16 + l15;
                int pb = (ks * 4 + quad) ^ (n & 7);
                bfr[i] = *(const bf16x8*)&Bsm[n * 64 + pb * 8];
            }
            #pragma unroll
            for (int i = 0; i < 4; i++)
                #pragma unroll
                for (int j = 0; j < 4; j++)
                    acc[i][j] = __builtin_amdgcn_mfma_f32_16x16x32_bf16(
                                    af[i], bfr[j], acc[i][j], 0, 0, 0);
        }
    }

    #pragma unroll
    for (int i = 0; i < 4; i++) {
        #pragma unroll
        for (int r = 0; r < 4; r++) {
            int row = row0 + wm * 64 + i * 16 + quad * 4 + r;
            if (row >= Mv) continue;
            #pragma unroll
            for (int j = 0; j < 4; j++) {
                int col = col0 + wn * 64 + j * 16 + l15;
                float v = acc[i][j][r];
                if (bias) v += bias[col];
                if (add)  v += add[(size_t)row * N + col];
                if (OB16) ((unsigned short*)C)[(size_t)row * N + col] = f2b(v);
                else      ((float*)C)[(size_t)row * N + col] = v;
            }
        }
    }
}

// ------------------------------ LayerNorm (fp32 in, bf16 out) --------------
__global__ __launch_bounds__(256) void ln_bf16(
    const float* __restrict__ x, const float* __restrict__ g,
    const float* __restrict__ b, unsigned short* __restrict__ y, int M)
{
    int wid = threadIdx.x >> 6, lane = threadIdx.x & 63;
    int row = blockIdx.x * 4 + wid;
    if (row >= M) return;
    const float4* xr = (const float4*)(x + (size_t)row * DM);
    float4 v0 = xr[lane * 2], v1 = xr[lane * 2 + 1];
    float s  = v0.x + v0.y + v0.z + v0.w + v1.x + v1.y + v1.z + v1.w;
    float s2 = v0.x*v0.x + v0.y*v0.y + v0.z*v0.z + v0.w*v0.w
             + v1.x*v1.x + v1.y*v1.y + v1.z*v1.z + v1.w*v1.w;
    #pragma unroll
    for (int off = 32; off >= 1; off >>= 1) {
        s  += __shfl_xor(s, off);
        s2 += __shfl_xor(s2, off);
    }
    float mu = s * (1.f / DM);
    float var = s2 * (1.f / DM) - mu * mu;
    float r = rsqrtf(var + LN_EPS);
    const float4* gv = (const float4*)g;
    const float4* bv = (const float4*)b;
    unsigned int* yr = (unsigned int*)(y + (size_t)row * DM);
    #pragma unroll
    for (int i = 0; i < 2; i++) {
        float4 v = (i == 0) ? v0 : v1;
        float4 gg = gv[lane * 2 + i], bb = bv[lane * 2 + i];
        float ox = (v.x - mu) * r * gg.x + bb.x;
        float oy = (v.y - mu) * r * gg.y + bb.y;
        float oz = (v.z - mu) * r * gg.z + bb.z;
        float ow = (v.w - mu) * r * gg.w + bb.w;
        yr[lane * 4 + i * 2 + 0] = pack2(ox, oy);
        yr[lane * 4 + i * 2 + 1] = pack2(oz, ow);
    }
}

// ------------------------------ time attention -----------------------------
__global__ __launch_bounds__(256, 2) void time_attn(
    const unsigned short* __restrict__ qkv, unsigned short* __restrict__ out)
{
    int t = blockIdx.x * 256 + threadIdx.x;
    if (t >= 8 * NP) return;
    int h = t / NP, j = t % NP;
    int pos = j % 1200;
    float q[64];
    const unsigned short* qp = qkv + (size_t)(j + 1) * QKV_ST + h * 64;
    #pragma unroll
    for (int d = 0; d < 64; d++) q[d] = b2f(qp[d]) * 0.125f;
    int rows[5] = {0, pos + 1, pos + 1201, pos + 2401, pos + 3601};
    float s[5];
    #pragma unroll
    for (int kk = 0; kk < 5; kk++) {
        const unsigned short* kp = qkv + (size_t)rows[kk] * QKV_ST + 512 + h * 64;
        float ss = 0.f;
        #pragma unroll
        for (int d = 0; d < 64; d++) ss += q[d] * b2f(kp[d]);
        s[kk] = ss;
    }
    float mx = s[0];
    #pragma unroll
    for (int kk = 1; kk < 5; kk++) mx = fmaxf(mx, s[kk]);
    float e[5], l = 0.f;
    #pragma unroll
    for (int kk = 0; kk < 5; kk++) { e[kk] = __expf(s[kk] - mx); l += e[kk]; }
    float rl = 1.f / l;
    float acc[64];
    #pragma unroll
    for (int d = 0; d < 64; d++) acc[d] = 0.f;
    #pragma unroll
    for (int kk = 0; kk < 5; kk++) {
        float p = e[kk] * rl;
        const unsigned short* vp = qkv + (size_t)rows[kk] * QKV_ST + 1024 + h * 64;
        #pragma unroll
        for (int d = 0; d < 64; d++) acc[d] += p * b2f(vp[d]);
    }
    unsigned int* op = (unsigned int*)(out + (size_t)(j + 1) * DM + h * 64);
    #pragma unroll
    for (int d2 = 0; d2 < 32; d2++) op[d2] = pack2(acc[2 * d2], acc[2 * d2 + 1]);
}

// ------------------------------ space attention ----------------------------
// block = (qchunk 0..2, head 0..7, f*2+half 0..7); 256 thr, 200 active queries.
#define SKT 100
__global__ __launch_bounds__(256, 2) void space_attn(
    const unsigned short* __restrict__ qkv, unsigned short* __restrict__ out)
{
    __shared__ float Kt[SKT][64];
    __shared__ float Vt[SKT][64];
    int qc = blockIdx.x, h = blockIdx.y, g = blockIdx.z;
    int f = g >> 1, half = g & 1;
    int t = threadIdx.x;
    bool act = t < 200;
    int qtok = 1 + f * 1200 + half * 600 + qc * 200 + t;
    int kb   = 1 + f * 1200 + (1 - half) * 600;

    float q[64], acc[64];
    float m = -1e30f, l = 0.f;
    if (act) {
        const unsigned short* qp = qkv + (size_t)qtok * QKV_ST + h * 64;
        #pragma unroll
        for (int d = 0; d < 64; d++) q[d] = b2f(qp[d]) * 0.125f;
        const unsigned short* ck = qkv + 512 + h * 64;   // cls key (row 0)
        float s = 0.f;
        #pragma unroll
        for (int d = 0; d < 64; d++) s += q[d] * b2f(ck[d]);
        m = s; l = 1.f;
        const unsigned short* cv = qkv + 1024 + h * 64;
        #pragma unroll
        for (int d = 0; d < 64; d++) acc[d] = b2f(cv[d]);
    }

    for (int kt = 0; kt < 6; kt++) {
        __syncthreads();
        for (int c = t; c < SKT * 8; c += 256) {
            int row = c >> 3, dc = (c & 7) * 8;
            const unsigned short* kp = qkv + (size_t)(kb + kt * SKT + row) * QKV_ST + 512 + h * 64 + dc;
            #pragma unroll
            for (int e = 0; e < 8; e++) Kt[row][dc + e] = b2f(kp[e]);
            const unsigned short* vp = kp + 512;
            #pragma unroll
            for (int e = 0; e < 8; e++) Vt[row][dc + e] = b2f(vp[e]);
        }
        __syncthreads();
        if (act) {
            for (int kk = 0; kk < SKT; kk++) {
                float s = 0.f;
                #pragma unroll
                for (int d = 0; d < 64; d++) s += q[d] * Kt[kk][d];
                float nm = fmaxf(m, s);
                float c = __expf(m - nm);
                float p = __expf(s - nm);
                l = l * c + p;
                #pragma unroll
                for (int d = 0; d < 64; d++) acc[d] = acc[d] * c + p * Vt[kk][d];
                m = nm;
            }
        }
    }
    if (act) {
        float rl = 1.f / l;
        unsigned int* op = (unsigned int*)(out + (size_t)qtok * DM + h * 64);
        #pragma unroll
        for (int d2 = 0; d2 < 32; d2++)
            op[d2] = pack2(acc[2 * d2] * rl, acc[2 * d2 + 1] * rl);
    }
}

// ------------------------------ cls attention ------------------------------
// 1 block (16 waves) per head; lane = dim; keys strided across waves, 2-key ILP.
__global__ __launch_bounds__(1024, 1) void cls_attn(
    const unsigned short* __restrict__ qkv, unsigned short* __restrict__ out)
{
    int h = blockIdx.x;
    int wid = threadIdx.x >> 6, lane = threadIdx.x & 63;
    __shared__ float sm[16], sl[16], sa[16][64];
    float qv = b2f(qkv[h * 64 + lane]) * 0.125f;
    float m = -1e30f, l = 0.f, acc = 0.f;
    for (int key = wid; key < NT; key += 32) {
        int k2 = key + 16;
        bool has2 = k2 < NT;
        const unsigned short* kr0 = qkv + (size_t)key * QKV_ST + 512 + h * 64;
        float x0 = b2f(kr0[lane]);
        float v0 = b2f(kr0[512 + lane]);
        float s0 = qv * x0;
        float s1 = 0.f, v1 = 0.f;
        if (has2) {
            const unsigned short* kr1 = qkv + (size_t)k2 * QKV_ST + 512 + h * 64;
            float x1 = b2f(kr1[lane]);
            v1 = b2f(kr1[512 + lane]);
            s1 = qv * x1;
        }
        #pragma unroll
        for (int off = 32; off >= 1; off >>= 1) {
            s0 += __shfl_xor(s0, off);
            s1 += __shfl_xor(s1, off);
        }
        float nm = fmaxf(m, s0);
        if (has2) nm = fmaxf(nm, s1);
        float c  = __expf(m - nm);
        float p0 = __expf(s0 - nm);
        float p1 = has2 ? __expf(s1 - nm) : 0.f;
        l   = l * c + p0 + p1;
        acc = acc * c + p0 * v0 + p1 * v1;
        m = nm;
    }
    if (lane == 0) { sm[wid] = m; sl[wid] = l; }
    sa[wid][lane] = acc;
    __syncthreads();
    if (wid == 0) {
        float M2 = -1e30f;
        #pragma unroll
        for (int i = 0; i < 16; i++) M2 = fmaxf(M2, sm[i]);
        float L = 0.f, o = 0.f;
        #pragma unroll
        for (int i = 0; i < 16; i++) {
            float c = __expf(sm[i] - M2);
            L += sl[i] * c;
            o += sa[i][lane] * c;
        }
        out[h * 64 + lane] = f2b(o / L);
    }
}

// ------------------------------ GeGLU (bf16 in/out) ------------------------
__global__ __launch_bounds__(256) void geglu_kernel(
    const unsigned short* __restrict__ h, unsigned short* __restrict__ out)
{
    int idx = blockIdx.x * 256 + threadIdx.x;       // 8-elem chunks over [NT,2048]
    if (idx >= NT * 256) return;
    int r = idx >> 8, cc = (idx & 255) * 8;
    const unsigned short* up = h + (size_t)r * 4096 + cc;
    const unsigned short* gp = up + 2048;
    float o[8];
    #pragma unroll
    for (int e = 0; e < 8; e++) {
        float u = b2f(up[e]), gg = b2f(gp[e]);
        o[e] = u * 0.5f * gg * (1.f + erff(gg * 0.70710678f));
    }
    unsigned int* op = (unsigned int*)(out + (size_t)r * 2048 + cc);
    #pragma unroll
    for (int e = 0; e < 4; e++) op[e] = pack2(o[2 * e], o[2 * e + 1]);
}

// ------------------------------ head ---------------------------------------
__global__ __launch_bounds__(64) void head_kernel(
    const float* __restrict__ x, const float* __restrict__ g,
    const float* __restrict__ b, const float* __restrict__ w,
    const float* __restrict__ ob, float* __restrict__ out)
{
    __shared__ float xn[DM];
    int lane = threadIdx.x;
    const float4* xr = (const float4*)x;
    float4 v0 = xr[lane * 2], v1 = xr[lane * 2 + 1];
    float s  = v0.x + v0.y + v0.z + v0.w + v1.x + v1.y + v1.z + v1.w;
    float s2 = v0.x*v0.x + v0.y*v0.y + v0.z*v0.z + v0.w*v0.w
             + v1.x*v1.x + v1.y*v1.y + v1.z*v1.z + v1.w*v1.w;
    #pragma unroll
    for (int off = 32; off >= 1; off >>= 1) {
        s  += __shfl_xor(s, off);
        s2 += __shfl_xor(s2, off);
    }
    float mu = s * (1.f / DM);
    float var = s2 * (1.f / DM) - mu * mu;
    float r = rsqrtf(var + LN_EPS);
    #pragma unroll
    for (int i = 0; i < 8; i++) {
        int d = lane * 8 + i;
        xn[d] = (x[d] - mu) * r * g[d] + b[d];
    }
    __syncthreads();
    if (lane < 60) {
        float a = ob[lane];
        for (int d = 0; d < DM; d++) a += xn[d] * w[d * 60 + lane];
        out[lane] = a;
    }
}

// ------------------------------ driver -------------------------------------
extern "C" void kernel_launch(void* const* d_in, const int* in_sizes, int n_in,
                              void* d_out, int out_size, void* d_ws, size_t ws_size,
                              hipStream_t stream)
{
    const float* video     = (const float*)d_in[0];
    const float* patch_w   = (const float*)d_in[1];
    const float* patch_b   = (const float*)d_in[2];
    const float* pos_emb   = (const float*)d_in[3];
    const float* cls_token = (const float*)d_in[4];
    const float* t_ln_g    = (const float*)d_in[5];
    const float* t_ln_b    = (const float*)d_in[6];
    const float* t_qkv_w   = (const float*)d_in[7];
    const float* t_out_w   = (const float*)d_in[8];
    const float* t_out_b   = (const float*)d_in[9];
    const float* s_ln_g    = (const float*)d_in[10];
    const float* s_ln_b    = (const float*)d_in[11];
    const float* s_qkv_w   = (const float*)d_in[12];
    const float* s_out_w   = (const float*)d_in[13];
    const float* s_out_b   = (const float*)d_in[14];
    const float* f_ln_g    = (const float*)d_in[15];
    const float* f_ln_b    = (const float*)d_in[16];
    const float* f_w1      = (const float*)d_in[17];
    const float* f_b1      = (const float*)d_in[18];
    const float* f_w2      = (const float*)d_in[19];
    const float* f_b2      = (const float*)d_in[20];
    const float* o_ln_g    = (const float*)d_in[21];
    const float* o_ln_b    = (const float*)d_in[22];
    const float* o_w       = (const float*)d_in[23];
    const float* o_b       = (const float*)d_in[24];

    char* ws = (char*)d_ws;
    size_t o = 0;
    float*          X    = (float*)(ws + o);          o += (size_t)(MP + 1) * 512 * 4;
    unsigned short* XN   = (unsigned short*)(ws + o); o += (size_t)MP * 512 * 2;
    unsigned short* QKV  = (unsigned short*)(ws + o); o += (size_t)MP * 1536 * 2;
    unsigned short* H16  = (unsigned short*)(ws + o); o += (size_t)MP * 4096 * 2;
    unsigned short* MID  = (unsigned short*)(ws + o); o += (size_t)MP * 2048 * 2;
    unsigned short* PT   = (unsigned short*)(ws + o); o += (size_t)MP * 768 * 2;
    unsigned short* W16  = (unsigned short*)(ws + o); o += (size_t)5242880 * 2;
    unsigned short* PW16 = (unsigned short*)(ws + o); o += (size_t)512 * 768 * 2;

    // ---- patch embed + cls + pos ----
    patchify_kernel<<<(NP * 768 + 255) / 256, 256, 0, stream>>>(video, PT);
    cls_init_kernel<<<2, 256, 0, stream>>>(cls_token, pos_emb, X);
    convertT_one<<<(768 / 32) * (512 / 32), 256, 0, stream>>>(patch_w, PW16, 768, 512);
    mfma_gemm<false><<<dim3(4, 38), 256, 0, stream>>>(PT, PW16, patch_b, pos_emb + DM,
                                                      X + DM, NP, DM, 768);

    dim3 g_qkv(12, 38), g_out(4, 38), g_ff1(32, 38), g_ff2(4, 38);
    for (int i = 0; i < 12; i++) {
        convertT_layer<<<5120, 256, 0, stream>>>(
            t_qkv_w + (size_t)i * 512 * 1536, t_out_w + (size_t)i * 512 * 512,
            s_qkv_w + (size_t)i * 512 * 1536, s_out_w + (size_t)i * 512 * 512,
            f_w1 + (size_t)i * 512 * 4096, f_w2 + (size_t)i * 2048 * 512, W16);

        // ---- time attention block ----
        ln_bf16<<<1201, 256, 0, stream>>>(X, t_ln_g + i * DM, t_ln_b + i * DM, XN, NT);
        mfma_gemm<true><<<g_qkv, 256, 0, stream>>>(XN, W16 + 0, nullptr, nullptr,
                                                   QKV, NT, QKV_ST, DM);
        time_attn<<<150, 256, 0, stream>>>(QKV, MID);
        cls_attn<<<8, 1024, 0, stream>>>(QKV, MID);
        mfma_gemm<false><<<g_out, 256, 0, stream>>>(MID, W16 + 786432, t_out_b + i * DM,
                                                    X, X, NT, DM, DM);
        // ---- space attention block ----
        ln_bf16<<<1201, 256, 0, stream>>>(X, s_ln_g + i * DM, s_ln_b + i * DM, XN, NT);
        mfma_gemm<true><<<g_qkv, 256, 0, stream>>>(XN, W16 + 1048576, nullptr, nullptr,
                                                   QKV, NT, QKV_ST, DM);
        space_attn<<<dim3(3, 8, 8), 256, 0, stream>>>(QKV, MID);
        cls_attn<<<8, 1024, 0, stream>>>(QKV, MID);
        mfma_gemm<false><<<g_out, 256, 0, stream>>>(MID, W16 + 1835008, s_out_b + i * DM,
                                                    X, X, NT, DM, DM);
        // ---- GeGLU FF block ----
        ln_bf16<<<1201, 256, 0, stream>>>(X, f_ln_g + i * DM, f_ln_b + i * DM, XN, NT);
        mfma_gemm<true><<<g_ff1, 256, 0, stream>>>(XN, W16 + 2097152, f_b1 + i * 4096,
                                                   nullptr, H16, NT, 4096, DM);
        geglu_kernel<<<(NT * 256 + 255) / 256, 256, 0, stream>>>(H16, MID);
        mfma_gemm<false><<<g_ff2, 256, 0, stream>>>(MID, W16 + 4194304, f_b2 + i * DM,
                                                    X, X, NT, DM, 2048);
    }

    head_kernel<<<1, 64, 0, stream>>>(X, o_ln_g, o_ln_b, o_w, o_b, (float*)d_out);
}

// Round 3
// 6565.273 us; speedup vs baseline: 5.9843x; 2.1578x over previous
//
#include <hip/hip_runtime.h>
#include <cmath>

// ---------------------------------------------------------------------------
// MutualTimeSformer — round 2: MFMA flash space-attention + vectorized time-attn
// Dims: B=1, F=4, n=1200/frame, N=4801 tokens (pad 4864), D=512, H=8, DH=64
// ---------------------------------------------------------------------------

#define NT      4801
#define NP      4800
#define MP      4864          // padded row count (38 * 128)
#define DM      512
#define QKV_ST  1536
#define LN_EPS  1e-5f

typedef __attribute__((ext_vector_type(8))) short bf16x8;
typedef __attribute__((ext_vector_type(4))) float f32x4;

__device__ __forceinline__ unsigned short f2b(float f) {
    union { float f; unsigned int u; } x; x.f = f;
    unsigned int r = (x.u + 0x7FFFu + ((x.u >> 16) & 1u)) >> 16;
    return (unsigned short)r;
}
__device__ __forceinline__ float b2f(unsigned short b) {
    union { unsigned int u; float f; } x; x.u = ((unsigned int)b) << 16;
    return x.f;
}
__device__ __forceinline__ unsigned int pack2(float a, float b) {
    return (unsigned int)f2b(a) | ((unsigned int)f2b(b) << 16);
}

__device__ __forceinline__ void gl_lds16(const void* g, void* l) {
    __builtin_amdgcn_global_load_lds(
        (__attribute__((address_space(1))) unsigned int*)(unsigned long long)(uintptr_t)g,
        (__attribute__((address_space(3))) unsigned int*)l, 16, 0, 0);
}

// ------------------------------ patchify (fp32 -> bf16) --------------------
__global__ void patchify_kernel(const float* __restrict__ video, unsigned short* __restrict__ out)
{
    int idx = blockIdx.x * 256 + threadIdx.x;
    if (idx >= NP * 768) return;
    int tok = idx / 768, e = idx % 768;
    int c  = e % 3;
    int pe = e / 3;
    int p2 = pe % 16, p1 = pe / 16;
    int half = tok / 2400, r = tok % 2400;
    int f = r / 600, rr = r % 600;
    int hi = rr / 20, wi = rr % 20;
    int row = hi * 16 + p1;
    int col = half * 320 + wi * 16 + p2;
    out[idx] = f2b(video[(((size_t)f * 3 + c) * 480 + row) * 640 + col]);
}

__global__ void cls_init_kernel(const float* __restrict__ cls_token,
                                const float* __restrict__ pos, float* __restrict__ X)
{
    int d = blockIdx.x * 256 + threadIdx.x;
    if (d < DM) X[d] = cls_token[d] + pos[d];
}

// ------------------------------ weight transpose-convert -------------------
__device__ __forceinline__ void transpose_tile(const float* __restrict__ in,
                                               unsigned short* __restrict__ out,
                                               int K, int N, int tile)
{
    __shared__ float T[32][33];
    int ntk = K / 32;
    int kt = tile % ntk, nt = tile / ntk;
    int k0 = kt * 32, n0 = nt * 32;
    int tx = threadIdx.x & 31, ty = threadIdx.x >> 5;
    #pragma unroll
    for (int i = 0; i < 4; i++)
        T[ty + 8 * i][tx] = in[(size_t)(k0 + ty + 8 * i) * N + n0 + tx];
    __syncthreads();
    #pragma unroll
    for (int i = 0; i < 4; i++)
        out[(size_t)(n0 + ty + 8 * i) * K + k0 + tx] = f2b(T[tx][ty + 8 * i]);
}

__global__ __launch_bounds__(256) void convertT_layer(
    const float* __restrict__ w0, const float* __restrict__ w1,
    const float* __restrict__ w2, const float* __restrict__ w3,
    const float* __restrict__ w4, const float* __restrict__ w5,
    unsigned short* __restrict__ out)
{
    int t = blockIdx.x;
    if      (t <  768) transpose_tile(w0, out + 0,       512, 1536, t);
    else if (t < 1024) transpose_tile(w1, out + 786432,  512,  512, t - 768);
    else if (t < 1792) transpose_tile(w2, out + 1048576, 512, 1536, t - 1024);
    else if (t < 2048) transpose_tile(w3, out + 1835008, 512,  512, t - 1792);
    else if (t < 4096) transpose_tile(w4, out + 2097152, 512, 4096, t - 2048);
    else               transpose_tile(w5, out + 4194304, 2048, 512, t - 4096);
}

__global__ __launch_bounds__(256) void convertT_one(
    const float* __restrict__ in, unsigned short* __restrict__ out, int K, int N)
{
    transpose_tile(in, out, K, N, blockIdx.x);
}

// ------------------------------ MFMA GEMM ----------------------------------
template<bool OB16>
__global__ __launch_bounds__(256, 2) void mfma_gemm(
    const unsigned short* __restrict__ A, const unsigned short* __restrict__ BT,
    const float* __restrict__ bias, const float* __restrict__ add,
    void* __restrict__ C, int Mv, int N, int K)
{
    __shared__ short Asm[128 * 64];
    __shared__ short Bsm[128 * 64];
    const int tid = threadIdx.x, w = tid >> 6, lane = tid & 63;
    const int row0 = blockIdx.y * 128, col0 = blockIdx.x * 128;
    const int wm = w >> 1, wn = w & 1;
    const int l15 = lane & 15, quad = lane >> 4;

    f32x4 acc[4][4] = {};

    int arows[4], aqs[4];
    #pragma unroll
    for (int i = 0; i < 4; i++) {
        int s = (w * 4 + i) * 64 + lane;
        arows[i] = s >> 3;
        aqs[i]   = (s & 7) ^ ((s >> 3) & 7);
    }

    for (int k0 = 0; k0 < K; k0 += 64) {
        __syncthreads();
        #pragma unroll
        for (int i = 0; i < 4; i++) {
            gl_lds16(A  + (size_t)(row0 + arows[i]) * K + k0 + aqs[i] * 8,
                     &Asm[(w * 4 + i) * 512]);
            gl_lds16(BT + (size_t)(col0 + arows[i]) * K + k0 + aqs[i] * 8,
                     &Bsm[(w * 4 + i) * 512]);
        }
        __syncthreads();
        #pragma unroll
        for (int ks = 0; ks < 2; ks++) {
            bf16x8 af[4], bfr[4];
            #pragma unroll
            for (int i = 0; i < 4; i++) {
                int m  = wm * 64 + i * 16 + l15;
                int pa = (ks * 4 + quad) ^ (m & 7);
                af[i]  = *(const bf16x8*)&Asm[m * 64 + pa * 8];
                int n  = wn * 64 + i * 16 + l15;
                int pb = (ks * 4 + quad) ^ (n & 7);
                bfr[i] = *(const bf16x8*)&Bsm[n * 64 + pb * 8];
            }
            #pragma unroll
            for (int i = 0; i < 4; i++)
                #pragma unroll
                for (int j = 0; j < 4; j++)
                    acc[i][j] = __builtin_amdgcn_mfma_f32_16x16x32_bf16(
                                    af[i], bfr[j], acc[i][j], 0, 0, 0);
        }
    }

    #pragma unroll
    for (int i = 0; i < 4; i++) {
        #pragma unroll
        for (int r = 0; r < 4; r++) {
            int row = row0 + wm * 64 + i * 16 + quad * 4 + r;
            if (row >= Mv) continue;
            #pragma unroll
            for (int j = 0; j < 4; j++) {
                int col = col0 + wn * 64 + j * 16 + l15;
                float v = acc[i][j][r];
                if (bias) v += bias[col];
                if (add)  v += add[(size_t)row * N + col];
                if (OB16) ((unsigned short*)C)[(size_t)row * N + col] = f2b(v);
                else      ((float*)C)[(size_t)row * N + col] = v;
            }
        }
    }
}

// ------------------------------ LayerNorm (fp32 in, bf16 out) --------------
__global__ __launch_bounds__(256) void ln_bf16(
    const float* __restrict__ x, const float* __restrict__ g,
    const float* __restrict__ b, unsigned short* __restrict__ y, int M)
{
    int wid = threadIdx.x >> 6, lane = threadIdx.x & 63;
    int row = blockIdx.x * 4 + wid;
    if (row >= M) return;
    const float4* xr = (const float4*)(x + (size_t)row * DM);
    float4 v0 = xr[lane * 2], v1 = xr[lane * 2 + 1];
    float s  = v0.x + v0.y + v0.z + v0.w + v1.x + v1.y + v1.z + v1.w;
    float s2 = v0.x*v0.x + v0.y*v0.y + v0.z*v0.z + v0.w*v0.w
             + v1.x*v1.x + v1.y*v1.y + v1.z*v1.z + v1.w*v1.w;
    #pragma unroll
    for (int off = 32; off >= 1; off >>= 1) {
        s  += __shfl_xor(s, off);
        s2 += __shfl_xor(s2, off);
    }
    float mu = s * (1.f / DM);
    float var = s2 * (1.f / DM) - mu * mu;
    float r = rsqrtf(var + LN_EPS);
    const float4* gv = (const float4*)g;
    const float4* bv = (const float4*)b;
    unsigned int* yr = (unsigned int*)(y + (size_t)row * DM);
    #pragma unroll
    for (int i = 0; i < 2; i++) {
        float4 v = (i == 0) ? v0 : v1;
        float4 gg = gv[lane * 2 + i], bb = bv[lane * 2 + i];
        float ox = (v.x - mu) * r * gg.x + bb.x;
        float oy = (v.y - mu) * r * gg.y + bb.y;
        float oz = (v.z - mu) * r * gg.z + bb.z;
        float ow = (v.w - mu) * r * gg.w + bb.w;
        yr[lane * 4 + i * 2 + 0] = pack2(ox, oy);
        yr[lane * 4 + i * 2 + 1] = pack2(oz, ow);
    }
}

// ------------------------------ time attention -----------------------------
__global__ __launch_bounds__(256, 2) void time_attn(
    const unsigned short* __restrict__ qkv, unsigned short* __restrict__ out)
{
    int t = blockIdx.x * 256 + threadIdx.x;
    if (t >= 8 * NP) return;
    int h = t / NP, j = t - h * NP;
    int pos = j % 1200;
    union { bf16x8 v; unsigned short u[8]; } ld;
    float q[64];
    const unsigned short* qp = qkv + (size_t)(j + 1) * QKV_ST + h * 64;
    #pragma unroll
    for (int c = 0; c < 8; c++) {
        ld.v = *(const bf16x8*)(qp + c * 8);
        #pragma unroll
        for (int e = 0; e < 8; e++) q[c * 8 + e] = b2f(ld.u[e]) * 0.125f;
    }
    int rows[5] = {0, pos + 1, pos + 1201, pos + 2401, pos + 3601};
    float s[5];
    #pragma unroll
    for (int kk = 0; kk < 5; kk++) {
        const unsigned short* kp = qkv + (size_t)rows[kk] * QKV_ST + 512 + h * 64;
        float ss = 0.f;
        #pragma unroll
        for (int c = 0; c < 8; c++) {
            ld.v = *(const bf16x8*)(kp + c * 8);
            #pragma unroll
            for (int e = 0; e < 8; e++) ss += q[c * 8 + e] * b2f(ld.u[e]);
        }
        s[kk] = ss;
    }
    float mx = s[0];
    #pragma unroll
    for (int kk = 1; kk < 5; kk++) mx = fmaxf(mx, s[kk]);
    float e5[5], l = 0.f;
    #pragma unroll
    for (int kk = 0; kk < 5; kk++) { e5[kk] = __expf(s[kk] - mx); l += e5[kk]; }
    float rl = 1.f / l;
    float acc[64];
    #pragma unroll
    for (int d = 0; d < 64; d++) acc[d] = 0.f;
    #pragma unroll
    for (int kk = 0; kk < 5; kk++) {
        float p = e5[kk] * rl;
        const unsigned short* vp = qkv + (size_t)rows[kk] * QKV_ST + 1024 + h * 64;
        #pragma unroll
        for (int c = 0; c < 8; c++) {
            ld.v = *(const bf16x8*)(vp + c * 8);
            #pragma unroll
            for (int e = 0; e < 8; e++) acc[c * 8 + e] += p * b2f(ld.u[e]);
        }
    }
    unsigned int* op = (unsigned int*)(out + (size_t)(j + 1) * DM + h * 64);
    #pragma unroll
    for (int d2 = 0; d2 < 32; d2++) op[d2] = pack2(acc[2 * d2], acc[2 * d2 + 1]);
}

// ------------------------------ space attention (MFMA flash) ----------------
// grid (qt 0..4, h 0..7, g=f*2+half 0..7); 4 waves/block, wave = 32 query rows.
// Keys per (f,half): 601 = cls + 600 other-half tokens; processed in 10 tiles of 64.
#define SPAD 72   // LDS row stride in halves (144 B: 16B-aligned, conflict-light)
__global__ __launch_bounds__(256, 2) void space_attn_mfma(
    const unsigned short* __restrict__ qkv, unsigned short* __restrict__ out)
{
    __shared__ short Ksm[64 * SPAD];          // K tile, natural [key][dh]
    __shared__ short VTsm[64 * SPAD];         // V tile transposed [dh][key]
    __shared__ short Psm[4][32 * SPAD];       // per-wave P round-trip
    int qt = blockIdx.x, h = blockIdx.y, g = blockIdx.z;
    int f = g >> 1, half = g & 1;
    int tid = threadIdx.x, w = tid >> 6, lane = tid & 63;
    int l15 = lane & 15, quad = lane >> 4;

    int qrow_base = qt * 128 + w * 32;                 // query row within 600 (may exceed)
    int qb = 1 + f * 1200 + half * 600;                // first query token
    int kb = 1 + f * 1200 + (1 - half) * 600;          // first non-cls key token

    // Q A-fragments (persistent): aQ[mfrag][kstep]
    bf16x8 aQ[2][2];
    #pragma unroll
    for (int mf = 0; mf < 2; mf++) {
        int qr = qrow_base + mf * 16 + l15;
        int qtok = qb + ((qr < 600) ? qr : 0);
        const unsigned short* qp = qkv + (size_t)qtok * QKV_ST + h * 64;
        #pragma unroll
        for (int ks = 0; ks < 2; ks++)
            aQ[mf][ks] = *(const bf16x8*)(qp + ks * 32 + quad * 8);
    }

    f32x4 O[2][4] = {};
    float mrow[2][4], lrow[2][4];
    #pragma unroll
    for (int mf = 0; mf < 2; mf++)
        #pragma unroll
        for (int r = 0; r < 4; r++) { mrow[mf][r] = -1e30f; lrow[mf][r] = 0.f; }

    for (int kt = 0; kt < 10; kt++) {
        __syncthreads();   // previous tile's K/V reads done
        // stage K (natural) and V (transposed); 512 8-half chunks, 2/thread
        #pragma unroll
        for (int it = 0; it < 2; it++) {
            int c = tid + it * 256;
            int row = c >> 3, dc = (c & 7) * 8;
            int kidx = kt * 64 + row;
            int tok = (kidx == 0) ? 0 : ((kidx <= 600) ? kb + kidx - 1 : 0);
            const unsigned short* kp = qkv + (size_t)tok * QKV_ST + 512 + h * 64 + dc;
            *(bf16x8*)&Ksm[row * SPAD + dc] = *(const bf16x8*)kp;
            union { bf16x8 v; unsigned short u[8]; } vv;
            vv.v = *(const bf16x8*)(kp + 512);
            #pragma unroll
            for (int e = 0; e < 8; e++)
                VTsm[(dc + e) * SPAD + row] = vv.u[e];
        }
        __syncthreads();

        // S = Q K^T (C-layout frags S[mf][nf])
        f32x4 S[2][4] = {};
        #pragma unroll
        for (int ks = 0; ks < 2; ks++) {
            bf16x8 bK[4];
            #pragma unroll
            for (int nf = 0; nf < 4; nf++)
                bK[nf] = *(const bf16x8*)&Ksm[(nf * 16 + l15) * SPAD + ks * 32 + quad * 8];
            #pragma unroll
            for (int mf = 0; mf < 2; mf++)
                #pragma unroll
                for (int nf = 0; nf < 4; nf++)
                    S[mf][nf] = __builtin_amdgcn_mfma_f32_16x16x32_bf16(
                                    aQ[mf][ks], bK[nf], S[mf][nf], 0, 0, 0);
        }

        // online softmax (row = quad*4+r within mfrag, col = nf*16+l15)
        #pragma unroll
        for (int mf = 0; mf < 2; mf++) {
            float pv[4][4];
            float lm[4] = {-1e30f, -1e30f, -1e30f, -1e30f};
            #pragma unroll
            for (int nf = 0; nf < 4; nf++) {
                int kidx = kt * 64 + nf * 16 + l15;
                bool valid = kidx <= 600;
                #pragma unroll
                for (int r = 0; r < 4; r++) {
                    float s = valid ? S[mf][nf][r] * 0.125f : -1e30f;
                    pv[nf][r] = s;
                    lm[r] = fmaxf(lm[r], s);
                }
            }
            #pragma unroll
            for (int off = 1; off < 16; off <<= 1)
                #pragma unroll
                for (int r = 0; r < 4; r++)
                    lm[r] = fmaxf(lm[r], __shfl_xor(lm[r], off));
            #pragma unroll
            for (int r = 0; r < 4; r++) {
                float nm = fmaxf(mrow[mf][r], lm[r]);
                float c = __expf(mrow[mf][r] - nm);
                mrow[mf][r] = nm;
                lrow[mf][r] *= c;
                #pragma unroll
                for (int nf = 0; nf < 4; nf++) O[mf][nf][r] *= c;
            }
            float rs[4] = {0.f, 0.f, 0.f, 0.f};
            #pragma unroll
            for (int nf = 0; nf < 4; nf++)
                #pragma unroll
                for (int r = 0; r < 4; r++) {
                    float p = __expf(pv[nf][r] - mrow[mf][r]);
                    pv[nf][r] = p;
                    rs[r] += p;
                }
            #pragma unroll
            for (int off = 1; off < 16; off <<= 1)
                #pragma unroll
                for (int r = 0; r < 4; r++)
                    rs[r] += __shfl_xor(rs[r], off);
            #pragma unroll
            for (int r = 0; r < 4; r++) lrow[mf][r] += rs[r];
            // P -> LDS (C-layout write)
            #pragma unroll
            for (int nf = 0; nf < 4; nf++)
                #pragma unroll
                for (int r = 0; r < 4; r++)
                    Psm[w][(mf * 16 + quad * 4 + r) * SPAD + nf * 16 + l15] = (short)f2b(pv[nf][r]);
        }
        asm volatile("s_waitcnt lgkmcnt(0)" ::: "memory");  // own-wave LDS RAW

        // O += P V
        #pragma unroll
        for (int ks2 = 0; ks2 < 2; ks2++) {
            bf16x8 aP[2], bV[4];
            #pragma unroll
            for (int mf = 0; mf < 2; mf++)
                aP[mf] = *(const bf16x8*)&Psm[w][(mf * 16 + l15) * SPAD + ks2 * 32 + quad * 8];
            #pragma unroll
            for (int nf = 0; nf < 4; nf++)
                bV[nf] = *(const bf16x8*)&VTsm[(nf * 16 + l15) * SPAD + ks2 * 32 + quad * 8];
            #pragma unroll
            for (int mf = 0; mf < 2; mf++)
                #pragma unroll
                for (int nf = 0; nf < 4; nf++)
                    O[mf][nf] = __builtin_amdgcn_mfma_f32_16x16x32_bf16(
                                    aP[mf], bV[nf], O[mf][nf], 0, 0, 0);
        }
    }

    // epilogue: O /= l, write bf16
    #pragma unroll
    for (int mf = 0; mf < 2; mf++)
        #pragma unroll
        for (int r = 0; r < 4; r++) {
            int qr = qrow_base + mf * 16 + quad * 4 + r;
            if (qr >= 600) continue;
            int qtok = qb + qr;
            float rl = 1.f / lrow[mf][r];
            #pragma unroll
            for (int nf = 0; nf < 4; nf++)
                out[(size_t)qtok * DM + h * 64 + nf * 16 + l15] = f2b(O[mf][nf][r] * rl);
        }
}

// ------------------------------ cls attention ------------------------------
__global__ __launch_bounds__(1024, 1) void cls_attn(
    const unsigned short* __restrict__ qkv, unsigned short* __restrict__ out)
{
    int h = blockIdx.x;
    int wid = threadIdx.x >> 6, lane = threadIdx.x & 63;
    __shared__ float sm[16], sl[16], sa[16][64];
    float qv = b2f(qkv[h * 64 + lane]) * 0.125f;
    float m = -1e30f, l = 0.f, acc = 0.f;
    for (int key = wid; key < NT; key += 32) {
        int k2 = key + 16;
        bool has2 = k2 < NT;
        const unsigned short* kr0 = qkv + (size_t)key * QKV_ST + 512 + h * 64;
        float x0 = b2f(kr0[lane]);
        float v0 = b2f(kr0[512 + lane]);
        float s0 = qv * x0;
        float s1 = 0.f, v1 = 0.f;
        if (has2) {
            const unsigned short* kr1 = qkv + (size_t)k2 * QKV_ST + 512 + h * 64;
            float x1 = b2f(kr1[lane]);
            v1 = b2f(kr1[512 + lane]);
            s1 = qv * x1;
        }
        #pragma unroll
        for (int off = 32; off >= 1; off >>= 1) {
            s0 += __shfl_xor(s0, off);
            s1 += __shfl_xor(s1, off);
        }
        float nm = fmaxf(m, s0);
        if (has2) nm = fmaxf(nm, s1);
        float c  = __expf(m - nm);
        float p0 = __expf(s0 - nm);
        float p1 = has2 ? __expf(s1 - nm) : 0.f;
        l   = l * c + p0 + p1;
        acc = acc * c + p0 * v0 + p1 * v1;
        m = nm;
    }
    if (lane == 0) { sm[wid] = m; sl[wid] = l; }
    sa[wid][lane] = acc;
    __syncthreads();
    if (wid == 0) {
        float M2 = -1e30f;
        #pragma unroll
        for (int i = 0; i < 16; i++) M2 = fmaxf(M2, sm[i]);
        float L = 0.f, o = 0.f;
        #pragma unroll
        for (int i = 0; i < 16; i++) {
            float c = __expf(sm[i] - M2);
            L += sl[i] * c;
            o += sa[i][lane] * c;
        }
        out[h * 64 + lane] = f2b(o / L);
    }
}

// ------------------------------ GeGLU (bf16 in/out) ------------------------
__global__ __launch_bounds__(256) void geglu_kernel(
    const unsigned short* __restrict__ h, unsigned short* __restrict__ out)
{
    int idx = blockIdx.x * 256 + threadIdx.x;
    if (idx >= NT * 256) return;
    int r = idx >> 8, cc = (idx & 255) * 8;
    const unsigned short* up = h + (size_t)r * 4096 + cc;
    const unsigned short* gp = up + 2048;
    float o[8];
    #pragma unroll
    for (int e = 0; e < 8; e++) {
        float u = b2f(up[e]), gg = b2f(gp[e]);
        o[e] = u * 0.5f * gg * (1.f + erff(gg * 0.70710678f));
    }
    unsigned int* op = (unsigned int*)(out + (size_t)r * 2048 + cc);
    #pragma unroll
    for (int e = 0; e < 4; e++) op[e] = pack2(o[2 * e], o[2 * e + 1]);
}

// ------------------------------ head ---------------------------------------
__global__ __launch_bounds__(64) void head_kernel(
    const float* __restrict__ x, const float* __restrict__ g,
    const float* __restrict__ b, const float* __restrict__ w,
    const float* __restrict__ ob, float* __restrict__ out)
{
    __shared__ float xn[DM];
    int lane = threadIdx.x;
    const float4* xr = (const float4*)x;
    float4 v0 = xr[lane * 2], v1 = xr[lane * 2 + 1];
    float s  = v0.x + v0.y + v0.z + v0.w + v1.x + v1.y + v1.z + v1.w;
    float s2 = v0.x*v0.x + v0.y*v0.y + v0.z*v0.z + v0.w*v0.w
             + v1.x*v1.x + v1.y*v1.y + v1.z*v1.z + v1.w*v1.w;
    #pragma unroll
    for (int off = 32; off >= 1; off >>= 1) {
        s  += __shfl_xor(s, off);
        s2 += __shfl_xor(s2, off);
    }
    float mu = s * (1.f / DM);
    float var = s2 * (1.f / DM) - mu * mu;
    float r = rsqrtf(var + LN_EPS);
    #pragma unroll
    for (int i = 0; i < 8; i++) {
        int d = lane * 8 + i;
        xn[d] = (x[d] - mu) * r * g[d] + b[d];
    }
    __syncthreads();
    if (lane < 60) {
        float a = ob[lane];
        for (int d = 0; d < DM; d++) a += xn[d] * w[d * 60 + lane];
        out[lane] = a;
    }
}

// ------------------------------ driver -------------------------------------
extern "C" void kernel_launch(void* const* d_in, const int* in_sizes, int n_in,
                              void* d_out, int out_size, void* d_ws, size_t ws_size,
                              hipStream_t stream)
{
    const float* video     = (const float*)d_in[0];
    const float* patch_w   = (const float*)d_in[1];
    const float* patch_b   = (const float*)d_in[2];
    const float* pos_emb   = (const float*)d_in[3];
    const float* cls_token = (const float*)d_in[4];
    const float* t_ln_g    = (const float*)d_in[5];
    const float* t_ln_b    = (const float*)d_in[6];
    const float* t_qkv_w   = (const float*)d_in[7];
    const float* t_out_w   = (const float*)d_in[8];
    const float* t_out_b   = (const float*)d_in[9];
    const float* s_ln_g    = (const float*)d_in[10];
    const float* s_ln_b    = (const float*)d_in[11];
    const float* s_qkv_w   = (const float*)d_in[12];
    const float* s_out_w   = (const float*)d_in[13];
    const float* s_out_b   = (const float*)d_in[14];
    const float* f_ln_g    = (const float*)d_in[15];
    const float* f_ln_b    = (const float*)d_in[16];
    const float* f_w1      = (const float*)d_in[17];
    const float* f_b1      = (const float*)d_in[18];
    const float* f_w2      = (const float*)d_in[19];
    const float* f_b2      = (const float*)d_in[20];
    const float* o_ln_g    = (const float*)d_in[21];
    const float* o_ln_b    = (const float*)d_in[22];
    const float* o_w       = (const float*)d_in[23];
    const float* o_b       = (const float*)d_in[24];

    char* ws = (char*)d_ws;
    size_t o = 0;
    float*          X    = (float*)(ws + o);          o += (size_t)(MP + 1) * 512 * 4;
    unsigned short* XN   = (unsigned short*)(ws + o); o += (size_t)MP * 512 * 2;
    unsigned short* QKV  = (unsigned short*)(ws + o); o += (size_t)MP * 1536 * 2;
    unsigned short* H16  = (unsigned short*)(ws + o); o += (size_t)MP * 4096 * 2;
    unsigned short* MID  = (unsigned short*)(ws + o); o += (size_t)MP * 2048 * 2;
    unsigned short* PT   = (unsigned short*)(ws + o); o += (size_t)MP * 768 * 2;
    unsigned short* W16  = (unsigned short*)(ws + o); o += (size_t)5242880 * 2;
    unsigned short* PW16 = (unsigned short*)(ws + o); o += (size_t)512 * 768 * 2;

    // ---- patch embed + cls + pos ----
    patchify_kernel<<<(NP * 768 + 255) / 256, 256, 0, stream>>>(video, PT);
    cls_init_kernel<<<2, 256, 0, stream>>>(cls_token, pos_emb, X);
    convertT_one<<<(768 / 32) * (512 / 32), 256, 0, stream>>>(patch_w, PW16, 768, 512);
    mfma_gemm<false><<<dim3(4, 38), 256, 0, stream>>>(PT, PW16, patch_b, pos_emb + DM,
                                                      X + DM, NP, DM, 768);

    dim3 g_qkv(12, 38), g_out(4, 38), g_ff1(32, 38), g_ff2(4, 38);
    for (int i = 0; i < 12; i++) {
        convertT_layer<<<5120, 256, 0, stream>>>(
            t_qkv_w + (size_t)i * 512 * 1536, t_out_w + (size_t)i * 512 * 512,
            s_qkv_w + (size_t)i * 512 * 1536, s_out_w + (size_t)i * 512 * 512,
            f_w1 + (size_t)i * 512 * 4096, f_w2 + (size_t)i * 2048 * 512, W16);

        // ---- time attention block ----
        ln_bf16<<<1201, 256, 0, stream>>>(X, t_ln_g + i * DM, t_ln_b + i * DM, XN, NT);
        mfma_gemm<true><<<g_qkv, 256, 0, stream>>>(XN, W16 + 0, nullptr, nullptr,
                                                   QKV, NT, QKV_ST, DM);
        time_attn<<<150, 256, 0, stream>>>(QKV, MID);
        cls_attn<<<8, 1024, 0, stream>>>(QKV, MID);
        mfma_gemm<false><<<g_out, 256, 0, stream>>>(MID, W16 + 786432, t_out_b + i * DM,
                                                    X, X, NT, DM, DM);
        // ---- space attention block ----
        ln_bf16<<<1201, 256, 0, stream>>>(X, s_ln_g + i * DM, s_ln_b + i * DM, XN, NT);
        mfma_gemm<true><<<g_qkv, 256, 0, stream>>>(XN, W16 + 1048576, nullptr, nullptr,
                                                   QKV, NT, QKV_ST, DM);
        space_attn_mfma<<<dim3(5, 8, 8), 256, 0, stream>>>(QKV, MID);
        cls_attn<<<8, 1024, 0, stream>>>(QKV, MID);
        mfma_gemm<false><<<g_out, 256, 0, stream>>>(MID, W16 + 1835008, s_out_b + i * DM,
                                                    X, X, NT, DM, DM);
        // ---- GeGLU FF block ----
        ln_bf16<<<1201, 256, 0, stream>>>(X, f_ln_g + i * DM, f_ln_b + i * DM, XN, NT);
        mfma_gemm<true><<<g_ff1, 256, 0, stream>>>(XN, W16 + 2097152, f_b1 + i * 4096,
                                                   nullptr, H16, NT, 4096, DM);
        geglu_kernel<<<(NT * 256 + 255) / 256, 256, 0, stream>>>(H16, MID);
        mfma_gemm<false><<<g_ff2, 256, 0, stream>>>(MID, W16 + 4194304, f_b2 + i * DM,
                                                    X, X, NT, DM, 2048);
    }

    head_kernel<<<1, 64, 0, stream>>>(X, o_ln_g, o_ln_b, o_w, o_b, (float*)d_out);
}

// Round 4
// 4653.066 us; speedup vs baseline: 8.4436x; 1.4110x over previous
//
#include <hip/hip_runtime.h>
#include <cmath>

// ---------------------------------------------------------------------------
// MutualTimeSformer — round 3: split-K cls attention (was 8-block starvation)
// Dims: B=1, F=4, n=1200/frame, N=4801 tokens (pad 4864), D=512, H=8, DH=64
// ---------------------------------------------------------------------------

#define NT      4801
#define NP      4800
#define MP      4864          // padded row count (38 * 128)
#define DM      512
#define QKV_ST  1536
#define LN_EPS  1e-5f
#define NCH     49            // cls split-K chunks (49*100 >= 4801)

typedef __attribute__((ext_vector_type(8))) short bf16x8;
typedef __attribute__((ext_vector_type(4))) float f32x4;

__device__ __forceinline__ unsigned short f2b(float f) {
    union { float f; unsigned int u; } x; x.f = f;
    unsigned int r = (x.u + 0x7FFFu + ((x.u >> 16) & 1u)) >> 16;
    return (unsigned short)r;
}
__device__ __forceinline__ float b2f(unsigned short b) {
    union { unsigned int u; float f; } x; x.u = ((unsigned int)b) << 16;
    return x.f;
}
__device__ __forceinline__ unsigned int pack2(float a, float b) {
    return (unsigned int)f2b(a) | ((unsigned int)f2b(b) << 16);
}

__device__ __forceinline__ void gl_lds16(const void* g, void* l) {
    __builtin_amdgcn_global_load_lds(
        (__attribute__((address_space(1))) unsigned int*)(unsigned long long)(uintptr_t)g,
        (__attribute__((address_space(3))) unsigned int*)l, 16, 0, 0);
}

// ------------------------------ patchify (fp32 -> bf16) --------------------
__global__ void patchify_kernel(const float* __restrict__ video, unsigned short* __restrict__ out)
{
    int idx = blockIdx.x * 256 + threadIdx.x;
    if (idx >= NP * 768) return;
    int tok = idx / 768, e = idx % 768;
    int c  = e % 3;
    int pe = e / 3;
    int p2 = pe % 16, p1 = pe / 16;
    int half = tok / 2400, r = tok % 2400;
    int f = r / 600, rr = r % 600;
    int hi = rr / 20, wi = rr % 20;
    int row = hi * 16 + p1;
    int col = half * 320 + wi * 16 + p2;
    out[idx] = f2b(video[(((size_t)f * 3 + c) * 480 + row) * 640 + col]);
}

__global__ void cls_init_kernel(const float* __restrict__ cls_token,
                                const float* __restrict__ pos, float* __restrict__ X)
{
    int d = blockIdx.x * 256 + threadIdx.x;
    if (d < DM) X[d] = cls_token[d] + pos[d];
}

// ------------------------------ weight transpose-convert -------------------
__device__ __forceinline__ void transpose_tile(const float* __restrict__ in,
                                               unsigned short* __restrict__ out,
                                               int K, int N, int tile)
{
    __shared__ float T[32][33];
    int ntk = K / 32;
    int kt = tile % ntk, nt = tile / ntk;
    int k0 = kt * 32, n0 = nt * 32;
    int tx = threadIdx.x & 31, ty = threadIdx.x >> 5;
    #pragma unroll
    for (int i = 0; i < 4; i++)
        T[ty + 8 * i][tx] = in[(size_t)(k0 + ty + 8 * i) * N + n0 + tx];
    __syncthreads();
    #pragma unroll
    for (int i = 0; i < 4; i++)
        out[(size_t)(n0 + ty + 8 * i) * K + k0 + tx] = f2b(T[tx][ty + 8 * i]);
}

__global__ __launch_bounds__(256) void convertT_layer(
    const float* __restrict__ w0, const float* __restrict__ w1,
    const float* __restrict__ w2, const float* __restrict__ w3,
    const float* __restrict__ w4, const float* __restrict__ w5,
    unsigned short* __restrict__ out)
{
    int t = blockIdx.x;
    if      (t <  768) transpose_tile(w0, out + 0,       512, 1536, t);
    else if (t < 1024) transpose_tile(w1, out + 786432,  512,  512, t - 768);
    else if (t < 1792) transpose_tile(w2, out + 1048576, 512, 1536, t - 1024);
    else if (t < 2048) transpose_tile(w3, out + 1835008, 512,  512, t - 1792);
    else if (t < 4096) transpose_tile(w4, out + 2097152, 512, 4096, t - 2048);
    else               transpose_tile(w5, out + 4194304, 2048, 512, t - 4096);
}

__global__ __launch_bounds__(256) void convertT_one(
    const float* __restrict__ in, unsigned short* __restrict__ out, int K, int N)
{
    transpose_tile(in, out, K, N, blockIdx.x);
}

// ------------------------------ MFMA GEMM ----------------------------------
template<bool OB16>
__global__ __launch_bounds__(256, 2) void mfma_gemm(
    const unsigned short* __restrict__ A, const unsigned short* __restrict__ BT,
    const float* __restrict__ bias, const float* __restrict__ add,
    void* __restrict__ C, int Mv, int N, int K)
{
    __shared__ short Asm[128 * 64];
    __shared__ short Bsm[128 * 64];
    const int tid = threadIdx.x, w = tid >> 6, lane = tid & 63;
    const int row0 = blockIdx.y * 128, col0 = blockIdx.x * 128;
    const int wm = w >> 1, wn = w & 1;
    const int l15 = lane & 15, quad = lane >> 4;

    f32x4 acc[4][4] = {};

    int arows[4], aqs[4];
    #pragma unroll
    for (int i = 0; i < 4; i++) {
        int s = (w * 4 + i) * 64 + lane;
        arows[i] = s >> 3;
        aqs[i]   = (s & 7) ^ ((s >> 3) & 7);
    }

    for (int k0 = 0; k0 < K; k0 += 64) {
        __syncthreads();
        #pragma unroll
        for (int i = 0; i < 4; i++) {
            gl_lds16(A  + (size_t)(row0 + arows[i]) * K + k0 + aqs[i] * 8,
                     &Asm[(w * 4 + i) * 512]);
            gl_lds16(BT + (size_t)(col0 + arows[i]) * K + k0 + aqs[i] * 8,
                     &Bsm[(w * 4 + i) * 512]);
        }
        __syncthreads();
        #pragma unroll
        for (int ks = 0; ks < 2; ks++) {
            bf16x8 af[4], bfr[4];
            #pragma unroll
            for (int i = 0; i < 4; i++) {
                int m  = wm * 64 + i * 16 + l15;
                int pa = (ks * 4 + quad) ^ (m & 7);
                af[i]  = *(const bf16x8*)&Asm[m * 64 + pa * 8];
                int n  = wn * 64 + i * 16 + l15;
                int pb = (ks * 4 + quad) ^ (n & 7);
                bfr[i] = *(const bf16x8*)&Bsm[n * 64 + pb * 8];
            }
            #pragma unroll
            for (int i = 0; i < 4; i++)
                #pragma unroll
                for (int j = 0; j < 4; j++)
                    acc[i][j] = __builtin_amdgcn_mfma_f32_16x16x32_bf16(
                                    af[i], bfr[j], acc[i][j], 0, 0, 0);
        }
    }

    #pragma unroll
    for (int i = 0; i < 4; i++) {
        #pragma unroll
        for (int r = 0; r < 4; r++) {
            int row = row0 + wm * 64 + i * 16 + quad * 4 + r;
            if (row >= Mv) continue;
            #pragma unroll
            for (int j = 0; j < 4; j++) {
                int col = col0 + wn * 64 + j * 16 + l15;
                float v = acc[i][j][r];
                if (bias) v += bias[col];
                if (add)  v += add[(size_t)row * N + col];
                if (OB16) ((unsigned short*)C)[(size_t)row * N + col] = f2b(v);
                else      ((float*)C)[(size_t)row * N + col] = v;
            }
        }
    }
}

// ------------------------------ LayerNorm (fp32 in, bf16 out) --------------
__global__ __launch_bounds__(256) void ln_bf16(
    const float* __restrict__ x, const float* __restrict__ g,
    const float* __restrict__ b, unsigned short* __restrict__ y, int M)
{
    int wid = threadIdx.x >> 6, lane = threadIdx.x & 63;
    int row = blockIdx.x * 4 + wid;
    if (row >= M) return;
    const float4* xr = (const float4*)(x + (size_t)row * DM);
    float4 v0 = xr[lane * 2], v1 = xr[lane * 2 + 1];
    float s  = v0.x + v0.y + v0.z + v0.w + v1.x + v1.y + v1.z + v1.w;
    float s2 = v0.x*v0.x + v0.y*v0.y + v0.z*v0.z + v0.w*v0.w
             + v1.x*v1.x + v1.y*v1.y + v1.z*v1.z + v1.w*v1.w;
    #pragma unroll
    for (int off = 32; off >= 1; off >>= 1) {
        s  += __shfl_xor(s, off);
        s2 += __shfl_xor(s2, off);
    }
    float mu = s * (1.f / DM);
    float var = s2 * (1.f / DM) - mu * mu;
    float r = rsqrtf(var + LN_EPS);
    const float4* gv = (const float4*)g;
    const float4* bv = (const float4*)b;
    unsigned int* yr = (unsigned int*)(y + (size_t)row * DM);
    #pragma unroll
    for (int i = 0; i < 2; i++) {
        float4 v = (i == 0) ? v0 : v1;
        float4 gg = gv[lane * 2 + i], bb = bv[lane * 2 + i];
        float ox = (v.x - mu) * r * gg.x + bb.x;
        float oy = (v.y - mu) * r * gg.y + bb.y;
        float oz = (v.z - mu) * r * gg.z + bb.z;
        float ow = (v.w - mu) * r * gg.w + bb.w;
        yr[lane * 4 + i * 2 + 0] = pack2(ox, oy);
        yr[lane * 4 + i * 2 + 1] = pack2(oz, ow);
    }
}

// ------------------------------ time attention -----------------------------
__global__ __launch_bounds__(256, 2) void time_attn(
    const unsigned short* __restrict__ qkv, unsigned short* __restrict__ out)
{
    int t = blockIdx.x * 256 + threadIdx.x;
    if (t >= 8 * NP) return;
    int h = t / NP, j = t - h * NP;
    int pos = j % 1200;
    union { bf16x8 v; unsigned short u[8]; } ld;
    float q[64];
    const unsigned short* qp = qkv + (size_t)(j + 1) * QKV_ST + h * 64;
    #pragma unroll
    for (int c = 0; c < 8; c++) {
        ld.v = *(const bf16x8*)(qp + c * 8);
        #pragma unroll
        for (int e = 0; e < 8; e++) q[c * 8 + e] = b2f(ld.u[e]) * 0.125f;
    }
    int rows[5] = {0, pos + 1, pos + 1201, pos + 2401, pos + 3601};
    float s[5];
    #pragma unroll
    for (int kk = 0; kk < 5; kk++) {
        const unsigned short* kp = qkv + (size_t)rows[kk] * QKV_ST + 512 + h * 64;
        float ss = 0.f;
        #pragma unroll
        for (int c = 0; c < 8; c++) {
            ld.v = *(const bf16x8*)(kp + c * 8);
            #pragma unroll
            for (int e = 0; e < 8; e++) ss += q[c * 8 + e] * b2f(ld.u[e]);
        }
        s[kk] = ss;
    }
    float mx = s[0];
    #pragma unroll
    for (int kk = 1; kk < 5; kk++) mx = fmaxf(mx, s[kk]);
    float e5[5], l = 0.f;
    #pragma unroll
    for (int kk = 0; kk < 5; kk++) { e5[kk] = __expf(s[kk] - mx); l += e5[kk]; }
    float rl = 1.f / l;
    float acc[64];
    #pragma unroll
    for (int d = 0; d < 64; d++) acc[d] = 0.f;
    #pragma unroll
    for (int kk = 0; kk < 5; kk++) {
        float p = e5[kk] * rl;
        const unsigned short* vp = qkv + (size_t)rows[kk] * QKV_ST + 1024 + h * 64;
        #pragma unroll
        for (int c = 0; c < 8; c++) {
            ld.v = *(const bf16x8*)(vp + c * 8);
            #pragma unroll
            for (int e = 0; e < 8; e++) acc[c * 8 + e] += p * b2f(ld.u[e]);
        }
    }
    unsigned int* op = (unsigned int*)(out + (size_t)(j + 1) * DM + h * 64);
    #pragma unroll
    for (int d2 = 0; d2 < 32; d2++) op[d2] = pack2(acc[2 * d2], acc[2 * d2 + 1]);
}

// ------------------------------ space attention (MFMA flash) ----------------
#define SPAD 72
__global__ __launch_bounds__(256, 2) void space_attn_mfma(
    const unsigned short* __restrict__ qkv, unsigned short* __restrict__ out)
{
    __shared__ short Ksm[64 * SPAD];
    __shared__ short VTsm[64 * SPAD];
    __shared__ short Psm[4][32 * SPAD];
    int qt = blockIdx.x, h = blockIdx.y, g = blockIdx.z;
    int f = g >> 1, half = g & 1;
    int tid = threadIdx.x, w = tid >> 6, lane = tid & 63;
    int l15 = lane & 15, quad = lane >> 4;

    int qrow_base = qt * 128 + w * 32;
    int qb = 1 + f * 1200 + half * 600;
    int kb = 1 + f * 1200 + (1 - half) * 600;

    bf16x8 aQ[2][2];
    #pragma unroll
    for (int mf = 0; mf < 2; mf++) {
        int qr = qrow_base + mf * 16 + l15;
        int qtok = qb + ((qr < 600) ? qr : 0);
        const unsigned short* qp = qkv + (size_t)qtok * QKV_ST + h * 64;
        #pragma unroll
        for (int ks = 0; ks < 2; ks++)
            aQ[mf][ks] = *(const bf16x8*)(qp + ks * 32 + quad * 8);
    }

    f32x4 O[2][4] = {};
    float mrow[2][4], lrow[2][4];
    #pragma unroll
    for (int mf = 0; mf < 2; mf++)
        #pragma unroll
        for (int r = 0; r < 4; r++) { mrow[mf][r] = -1e30f; lrow[mf][r] = 0.f; }

    for (int kt = 0; kt < 10; kt++) {
        __syncthreads();
        #pragma unroll
        for (int it = 0; it < 2; it++) {
            int c = tid + it * 256;
            int row = c >> 3, dc = (c & 7) * 8;
            int kidx = kt * 64 + row;
            int tok = (kidx == 0) ? 0 : ((kidx <= 600) ? kb + kidx - 1 : 0);
            const unsigned short* kp = qkv + (size_t)tok * QKV_ST + 512 + h * 64 + dc;
            *(bf16x8*)&Ksm[row * SPAD + dc] = *(const bf16x8*)kp;
            union { bf16x8 v; unsigned short u[8]; } vv;
            vv.v = *(const bf16x8*)(kp + 512);
            #pragma unroll
            for (int e = 0; e < 8; e++)
                VTsm[(dc + e) * SPAD + row] = vv.u[e];
        }
        __syncthreads();

        f32x4 S[2][4] = {};
        #pragma unroll
        for (int ks = 0; ks < 2; ks++) {
            bf16x8 bK[4];
            #pragma unroll
            for (int nf = 0; nf < 4; nf++)
                bK[nf] = *(const bf16x8*)&Ksm[(nf * 16 + l15) * SPAD + ks * 32 + quad * 8];
            #pragma unroll
            for (int mf = 0; mf < 2; mf++)
                #pragma unroll
                for (int nf = 0; nf < 4; nf++)
                    S[mf][nf] = __builtin_amdgcn_mfma_f32_16x16x32_bf16(
                                    aQ[mf][ks], bK[nf], S[mf][nf], 0, 0, 0);
        }

        #pragma unroll
        for (int mf = 0; mf < 2; mf++) {
            float pv[4][4];
            float lm[4] = {-1e30f, -1e30f, -1e30f, -1e30f};
            #pragma unroll
            for (int nf = 0; nf < 4; nf++) {
                int kidx = kt * 64 + nf * 16 + l15;
                bool valid = kidx <= 600;
                #pragma unroll
                for (int r = 0; r < 4; r++) {
                    float s = valid ? S[mf][nf][r] * 0.125f : -1e30f;
                    pv[nf][r] = s;
                    lm[r] = fmaxf(lm[r], s);
                }
            }
            #pragma unroll
            for (int off = 1; off < 16; off <<= 1)
                #pragma unroll
                for (int r = 0; r < 4; r++)
                    lm[r] = fmaxf(lm[r], __shfl_xor(lm[r], off));
            #pragma unroll
            for (int r = 0; r < 4; r++) {
                float nm = fmaxf(mrow[mf][r], lm[r]);
                float c = __expf(mrow[mf][r] - nm);
                mrow[mf][r] = nm;
                lrow[mf][r] *= c;
                #pragma unroll
                for (int nf = 0; nf < 4; nf++) O[mf][nf][r] *= c;
            }
            float rs[4] = {0.f, 0.f, 0.f, 0.f};
            #pragma unroll
            for (int nf = 0; nf < 4; nf++)
                #pragma unroll
                for (int r = 0; r < 4; r++) {
                    float p = __expf(pv[nf][r] - mrow[mf][r]);
                    pv[nf][r] = p;
                    rs[r] += p;
                }
            #pragma unroll
            for (int off = 1; off < 16; off <<= 1)
                #pragma unroll
                for (int r = 0; r < 4; r++)
                    rs[r] += __shfl_xor(rs[r], off);
            #pragma unroll
            for (int r = 0; r < 4; r++) lrow[mf][r] += rs[r];
            #pragma unroll
            for (int nf = 0; nf < 4; nf++)
                #pragma unroll
                for (int r = 0; r < 4; r++)
                    Psm[w][(mf * 16 + quad * 4 + r) * SPAD + nf * 16 + l15] = (short)f2b(pv[nf][r]);
        }
        asm volatile("s_waitcnt lgkmcnt(0)" ::: "memory");

        #pragma unroll
        for (int ks2 = 0; ks2 < 2; ks2++) {
            bf16x8 aP[2], bV[4];
            #pragma unroll
            for (int mf = 0; mf < 2; mf++)
                aP[mf] = *(const bf16x8*)&Psm[w][(mf * 16 + l15) * SPAD + ks2 * 32 + quad * 8];
            #pragma unroll
            for (int nf = 0; nf < 4; nf++)
                bV[nf] = *(const bf16x8*)&VTsm[(nf * 16 + l15) * SPAD + ks2 * 32 + quad * 8];
            #pragma unroll
            for (int mf = 0; mf < 2; mf++)
                #pragma unroll
                for (int nf = 0; nf < 4; nf++)
                    O[mf][nf] = __builtin_amdgcn_mfma_f32_16x16x32_bf16(
                                    aP[mf], bV[nf], O[mf][nf], 0, 0, 0);
        }
    }

    #pragma unroll
    for (int mf = 0; mf < 2; mf++)
        #pragma unroll
        for (int r = 0; r < 4; r++) {
            int qr = qrow_base + mf * 16 + quad * 4 + r;
            if (qr >= 600) continue;
            int qtok = qb + qr;
            float rl = 1.f / lrow[mf][r];
            #pragma unroll
            for (int nf = 0; nf < 4; nf++)
                out[(size_t)qtok * DM + h * 64 + nf * 16 + l15] = f2b(O[mf][nf][r] * rl);
        }
}

// ------------------------------ cls attention (split-K) --------------------
// stage 1: grid (NCH, 8); block 256 = 4 waves; wave = 25 keys; partial per block.
// partial layout [h][chunk]: {m, l, pad, pad, acc[64]} stride 68 floats.
__global__ __launch_bounds__(256) void cls_attn_part(
    const unsigned short* __restrict__ qkv, float* __restrict__ part)
{
    int ch = blockIdx.x, h = blockIdx.y;
    int wid = threadIdx.x >> 6, lane = threadIdx.x & 63;
    __shared__ float sm[4], sl[4], sa[4][64];
    float qv = b2f(qkv[h * 64 + lane]) * 0.125f;
    int k0 = ch * 100 + wid * 25;
    float m = -1e30f, l = 0.f, acc = 0.f;
    for (int i = 0; i < 25; i += 2) {
        int key0 = k0 + i, key1 = key0 + 1;
        bool ok0 = key0 < NT;
        bool ok1 = (i + 1 < 25) && (key1 < NT);
        const unsigned short* kr0 = qkv + (size_t)(ok0 ? key0 : 0) * QKV_ST + 512 + h * 64;
        const unsigned short* kr1 = qkv + (size_t)(ok1 ? key1 : 0) * QKV_ST + 512 + h * 64;
        float s0 = qv * b2f(kr0[lane]);
        float v0 = b2f(kr0[512 + lane]);
        float s1 = qv * b2f(kr1[lane]);
        float v1 = b2f(kr1[512 + lane]);
        #pragma unroll
        for (int off = 32; off >= 1; off >>= 1) {
            s0 += __shfl_xor(s0, off);
            s1 += __shfl_xor(s1, off);
        }
        float nm = m;
        if (ok0) nm = fmaxf(nm, s0);
        if (ok1) nm = fmaxf(nm, s1);
        float c  = __expf(m - nm);
        float p0 = ok0 ? __expf(s0 - nm) : 0.f;
        float p1 = ok1 ? __expf(s1 - nm) : 0.f;
        l   = l * c + p0 + p1;
        acc = acc * c + p0 * v0 + p1 * v1;
        m = nm;
    }
    if (lane == 0) { sm[wid] = m; sl[wid] = l; }
    sa[wid][lane] = acc;
    __syncthreads();
    if (wid == 0) {
        float M2 = fmaxf(fmaxf(sm[0], sm[1]), fmaxf(sm[2], sm[3]));
        float L = 0.f, o = 0.f;
        #pragma unroll
        for (int w = 0; w < 4; w++) {
            float c = __expf(sm[w] - M2);
            L += sl[w] * c;
            o += sa[w][lane] * c;
        }
        float* p = part + ((size_t)h * NCH + ch) * 68;
        if (lane == 0) { p[0] = M2; p[1] = L; }
        p[4 + lane] = o;
    }
}

// stage 2: 8 blocks x 64 lanes; merge NCH partials per head.
__global__ __launch_bounds__(64) void cls_attn_reduce(
    const float* __restrict__ part, unsigned short* __restrict__ out)
{
    int h = blockIdx.x, lane = threadIdx.x;
    float m = -1e30f, l = 0.f, acc = 0.f;
    for (int c = 0; c < NCH; c++) {
        const float* p = part + ((size_t)h * NCH + c) * 68;
        float cm = p[0], cl = p[1], ca = p[4 + lane];
        float nm = fmaxf(m, cm);
        float e1 = __expf(m - nm), e2 = __expf(cm - nm);
        l   = l * e1 + cl * e2;
        acc = acc * e1 + ca * e2;
        m = nm;
    }
    out[h * 64 + lane] = f2b(acc / l);
}

// ------------------------------ GeGLU (bf16 in/out) ------------------------
__global__ __launch_bounds__(256) void geglu_kernel(
    const unsigned short* __restrict__ h, unsigned short* __restrict__ out)
{
    int idx = blockIdx.x * 256 + threadIdx.x;
    if (idx >= NT * 256) return;
    int r = idx >> 8, cc = (idx & 255) * 8;
    const unsigned short* up = h + (size_t)r * 4096 + cc;
    const unsigned short* gp = up + 2048;
    float o[8];
    #pragma unroll
    for (int e = 0; e < 8; e++) {
        float u = b2f(up[e]), gg = b2f(gp[e]);
        o[e] = u * 0.5f * gg * (1.f + erff(gg * 0.70710678f));
    }
    unsigned int* op = (unsigned int*)(out + (size_t)r * 2048 + cc);
    #pragma unroll
    for (int e = 0; e < 4; e++) op[e] = pack2(o[2 * e], o[2 * e + 1]);
}

// ------------------------------ head ---------------------------------------
__global__ __launch_bounds__(64) void head_kernel(
    const float* __restrict__ x, const float* __restrict__ g,
    const float* __restrict__ b, const float* __restrict__ w,
    const float* __restrict__ ob, float* __restrict__ out)
{
    __shared__ float xn[DM];
    int lane = threadIdx.x;
    const float4* xr = (const float4*)x;
    float4 v0 = xr[lane * 2], v1 = xr[lane * 2 + 1];
    float s  = v0.x + v0.y + v0.z + v0.w + v1.x + v1.y + v1.z + v1.w;
    float s2 = v0.x*v0.x + v0.y*v0.y + v0.z*v0.z + v0.w*v0.w
             + v1.x*v1.x + v1.y*v1.y + v1.z*v1.z + v1.w*v1.w;
    #pragma unroll
    for (int off = 32; off >= 1; off >>= 1) {
        s  += __shfl_xor(s, off);
        s2 += __shfl_xor(s2, off);
    }
    float mu = s * (1.f / DM);
    float var = s2 * (1.f / DM) - mu * mu;
    float r = rsqrtf(var + LN_EPS);
    #pragma unroll
    for (int i = 0; i < 8; i++) {
        int d = lane * 8 + i;
        xn[d] = (x[d] - mu) * r * g[d] + b[d];
    }
    __syncthreads();
    if (lane < 60) {
        float a = ob[lane];
        for (int d = 0; d < DM; d++) a += xn[d] * w[d * 60 + lane];
        out[lane] = a;
    }
}

// ------------------------------ driver -------------------------------------
extern "C" void kernel_launch(void* const* d_in, const int* in_sizes, int n_in,
                              void* d_out, int out_size, void* d_ws, size_t ws_size,
                              hipStream_t stream)
{
    const float* video     = (const float*)d_in[0];
    const float* patch_w   = (const float*)d_in[1];
    const float* patch_b   = (const float*)d_in[2];
    const float* pos_emb   = (const float*)d_in[3];
    const float* cls_token = (const float*)d_in[4];
    const float* t_ln_g    = (const float*)d_in[5];
    const float* t_ln_b    = (const float*)d_in[6];
    const float* t_qkv_w   = (const float*)d_in[7];
    const float* t_out_w   = (const float*)d_in[8];
    const float* t_out_b   = (const float*)d_in[9];
    const float* s_ln_g    = (const float*)d_in[10];
    const float* s_ln_b    = (const float*)d_in[11];
    const float* s_qkv_w   = (const float*)d_in[12];
    const float* s_out_w   = (const float*)d_in[13];
    const float* s_out_b   = (const float*)d_in[14];
    const float* f_ln_g    = (const float*)d_in[15];
    const float* f_ln_b    = (const float*)d_in[16];
    const float* f_w1      = (const float*)d_in[17];
    const float* f_b1      = (const float*)d_in[18];
    const float* f_w2      = (const float*)d_in[19];
    const float* f_b2      = (const float*)d_in[20];
    const float* o_ln_g    = (const float*)d_in[21];
    const float* o_ln_b    = (const float*)d_in[22];
    const float* o_w       = (const float*)d_in[23];
    const float* o_b       = (const float*)d_in[24];

    char* ws = (char*)d_ws;
    size_t o = 0;
    float*          X    = (float*)(ws + o);          o += (size_t)(MP + 1) * 512 * 4;
    unsigned short* XN   = (unsigned short*)(ws + o); o += (size_t)MP * 512 * 2;
    unsigned short* QKV  = (unsigned short*)(ws + o); o += (size_t)MP * 1536 * 2;
    unsigned short* H16  = (unsigned short*)(ws + o); o += (size_t)MP * 4096 * 2;
    unsigned short* MID  = (unsigned short*)(ws + o); o += (size_t)MP * 2048 * 2;
    unsigned short* PT   = (unsigned short*)(ws + o); o += (size_t)MP * 768 * 2;
    unsigned short* W16  = (unsigned short*)(ws + o); o += (size_t)5242880 * 2;
    unsigned short* PW16 = (unsigned short*)(ws + o); o += (size_t)512 * 768 * 2;
    float*          CP   = (float*)(ws + o);          o += (size_t)8 * NCH * 68 * 4;

    // ---- patch embed + cls + pos ----
    patchify_kernel<<<(NP * 768 + 255) / 256, 256, 0, stream>>>(video, PT);
    cls_init_kernel<<<2, 256, 0, stream>>>(cls_token, pos_emb, X);
    convertT_one<<<(768 / 32) * (512 / 32), 256, 0, stream>>>(patch_w, PW16, 768, 512);
    mfma_gemm<false><<<dim3(4, 38), 256, 0, stream>>>(PT, PW16, patch_b, pos_emb + DM,
                                                      X + DM, NP, DM, 768);

    dim3 g_qkv(12, 38), g_out(4, 38), g_ff1(32, 38), g_ff2(4, 38);
    for (int i = 0; i < 12; i++) {
        convertT_layer<<<5120, 256, 0, stream>>>(
            t_qkv_w + (size_t)i * 512 * 1536, t_out_w + (size_t)i * 512 * 512,
            s_qkv_w + (size_t)i * 512 * 1536, s_out_w + (size_t)i * 512 * 512,
            f_w1 + (size_t)i * 512 * 4096, f_w2 + (size_t)i * 2048 * 512, W16);

        // ---- time attention block ----
        ln_bf16<<<1201, 256, 0, stream>>>(X, t_ln_g + i * DM, t_ln_b + i * DM, XN, NT);
        mfma_gemm<true><<<g_qkv, 256, 0, stream>>>(XN, W16 + 0, nullptr, nullptr,
                                                   QKV, NT, QKV_ST, DM);
        time_attn<<<150, 256, 0, stream>>>(QKV, MID);
        cls_attn_part<<<dim3(NCH, 8), 256, 0, stream>>>(QKV, CP);
        cls_attn_reduce<<<8, 64, 0, stream>>>(CP, MID);
        mfma_gemm<false><<<g_out, 256, 0, stream>>>(MID, W16 + 786432, t_out_b + i * DM,
                                                    X, X, NT, DM, DM);
        // ---- space attention block ----
        ln_bf16<<<1201, 256, 0, stream>>>(X, s_ln_g + i * DM, s_ln_b + i * DM, XN, NT);
        mfma_gemm<true><<<g_qkv, 256, 0, stream>>>(XN, W16 + 1048576, nullptr, nullptr,
                                                   QKV, NT, QKV_ST, DM);
        space_attn_mfma<<<dim3(5, 8, 8), 256, 0, stream>>>(QKV, MID);
        cls_attn_part<<<dim3(NCH, 8), 256, 0, stream>>>(QKV, CP);
        cls_attn_reduce<<<8, 64, 0, stream>>>(CP, MID);
        mfma_gemm<false><<<g_out, 256, 0, stream>>>(MID, W16 + 1835008, s_out_b + i * DM,
                                                    X, X, NT, DM, DM);
        // ---- GeGLU FF block ----
        ln_bf16<<<1201, 256, 0, stream>>>(X, f_ln_g + i * DM, f_ln_b + i * DM, XN, NT);
        mfma_gemm<true><<<g_ff1, 256, 0, stream>>>(XN, W16 + 2097152, f_b1 + i * 4096,
                                                   nullptr, H16, NT, 4096, DM);
        geglu_kernel<<<(NT * 256 + 255) / 256, 256, 0, stream>>>(H16, MID);
        mfma_gemm<false><<<g_ff2, 256, 0, stream>>>(MID, W16 + 4194304, f_b2 + i * DM,
                                                    X, X, NT, DM, 2048);
    }

    head_kernel<<<1, 64, 0, stream>>>(X, o_ln_g, o_ln_b, o_w, o_b, (float*)d_out);
}